// Round 6
// baseline (586.562 us; speedup 1.0000x reference)
//
#include <hip/hip_runtime.h>

#define NN 3072
#define CCC 16
#define HH 128
#define KTOP 4
#define NCLS 455   // C(15,3)
#define NUP 120
#define EPSF 1e-5f

// ---------------- ws layout (float offsets) ----------------
#define OFF_F       0
#define SZ_F        (16*NCLS*HH)            // 931840
#define OFF_CNT     (OFF_F + SZ_F)
#define SZ_CNT      (16*NCLS)
#define OFF_SUMS    (OFF_CNT + SZ_CNT)
#define SZ_SUMS     32
#define OFF_NCNT    (OFF_SUMS + SZ_SUMS)    // int nodeCnt[16*16] (64B-padded)
#define SZ_NCNT     256
#define OFF_BAR     (OFF_NCNT + SZ_NCNT)    // int bar[2]: count, generation
#define SZ_BAR      64
#define OFF_COLS    (OFF_BAR + SZ_BAR)
#define SZ_E        (NN*KTOP)
#define OFF_RANKS   (OFF_COLS + SZ_E)
#define OFF_FISEL   (OFF_RANKS + SZ_E)
#define OFF_NLIST   (OFF_FISEL + SZ_E)
#define SZ_NLIST    (16*NN)
#define OFF_AGG     (OFF_NLIST + SZ_NLIST)
#define OFF_HC      (OFF_AGG + SZ_F)
#define SZ_HC       (NN*KTOP*HH)
#define OFF_HALF    (OFF_HC + SZ_HC)
#define HOFF_W1H    0
#define HOFF_W1L    16384
#define HOFF_WLH    32768
#define HOFF_WRH    (32768 + 262144)

#define GRID 384
#define MT 64
#define GCP 8

typedef _Float16 h8 __attribute__((ext_vector_type(8)));
typedef float    f4 __attribute__((ext_vector_type(4)));

__device__ __forceinline__ int C2i(int x){ return x*(x-1)/2; }
__device__ __forceinline__ int C3i(int x){ return x*(x-1)*(x-2)/6; }

// -------- device-scope generation barrier (agent scope = cross-XCD safe) --------
__device__ __forceinline__ void gbar(int* bar){
  __syncthreads();
  if (threadIdx.x == 0){
    int g = __hip_atomic_load(bar+1, __ATOMIC_RELAXED, __HIP_MEMORY_SCOPE_AGENT);
    int a = __hip_atomic_fetch_add(bar, 1, __ATOMIC_ACQ_REL, __HIP_MEMORY_SCOPE_AGENT);
    if (a == GRID-1){
      __hip_atomic_store(bar, 0, __ATOMIC_RELAXED, __HIP_MEMORY_SCOPE_AGENT);
      __hip_atomic_fetch_add(bar+1, 1, __ATOMIC_RELEASE, __HIP_MEMORY_SCOPE_AGENT);
    } else {
      while (__hip_atomic_load(bar+1, __ATOMIC_ACQUIRE, __HIP_MEMORY_SCOPE_AGENT) == g){
        __builtin_amdgcn_s_sleep(8);
      }
    }
  }
  __syncthreads();
}

// -------- init: zero barrier + sums (ws is re-poisoned between iterations) --------
__global__ __launch_bounds__(64) void k_init(float* __restrict__ ws){
  int t = threadIdx.x;
  if (t < 2)  ((int*)(ws + OFF_BAR))[t] = 0;
  if (t < 32) ws[OFF_SUMS + t] = 0.f;
}

// ================== ONE mega-kernel: 7 stages, 6 device barriers ==================
__global__ __launch_bounds__(256, 2) void k_mega(
    const float* __restrict__ X,  const float* __restrict__ W1,
    const float* __restrict__ b1, const float* __restrict__ ln_g,
    const float* __restrict__ ln_b,const float* __restrict__ W2,
    const float* __restrict__ b2, const float* __restrict__ Wl,
    const float* __restrict__ bl, const float* __restrict__ Wr,
    float* __restrict__ ws, float* __restrict__ out)
{
  __shared__ __align__(16) float SM[6144];   // 24 KB union, re-aliased per stage
  int t = threadIdx.x;
  int bid = blockIdx.x;
  int w = t >> 6;
  int lane = t & 63;
  int l15 = lane & 15, quad = lane >> 4;

  float* F      = ws + OFF_F;
  float* cnt    = ws + OFF_CNT;
  float* sums   = ws + OFF_SUMS;
  int*   nodeCnt= (int*)(ws + OFF_NCNT);
  int*   bar    = (int*)(ws + OFF_BAR);
  int*   cols   = (int*)(ws + OFF_COLS);
  int*   ranks  = (int*)(ws + OFF_RANKS);
  float* fiSel  = ws + OFF_FISEL;
  int*   nodeList=(int*)(ws + OFF_NLIST);
  float* agg    = ws + OFF_AGG;
  float* hcBuf  = ws + OFF_HC;
  _Float16* hbase = (_Float16*)(ws + OFF_HALF);

  // ---------------- S0: W1 -> f16 hi/lo (Wl/Wr converted later, overlapped) ----------------
  {
    int i = bid*256 + t;
    if (i < 16384){
      float x = W1[i];
      _Float16 h = (_Float16)x;
      hbase[HOFF_W1H + i] = h;
      hbase[HOFF_W1L + i] = (_Float16)(x - (float)h);
    }
  }
  gbar(bar);

  // ---------------- S1: logits (MFMA hi/lo) -> in-LDS topk/softmax ----------------
  {
    const _Float16* W1h = hbase + HOFF_W1H;
    const _Float16* W1l = hbase + HOFF_W1L;
    float* llog = SM;   // 64 floats
    for (int vb = bid; vb < NN*CCC/MT; vb += GRID){
      int base = vb * MT;
      int mA = base + 16*w + l15;
      const float* xrow = X + (size_t)mA*HH;
      h8 ah[4], al[4];
      #pragma unroll
      for (int c=0;c<4;++c){
        float4 u = *(const float4*)(xrow + c*32 + quad*8);
        float4 v = *(const float4*)(xrow + c*32 + quad*8 + 4);
        float xv[8] = {u.x,u.y,u.z,u.w,v.x,v.y,v.z,v.w};
        #pragma unroll
        for (int j=0;j<8;++j){
          _Float16 hi = (_Float16)xv[j];
          ah[c][j] = hi;
          al[c][j] = (_Float16)(xv[j] - (float)hi);
        }
      }
      f4 acc[8];
      #pragma unroll
      for (int nt=0;nt<8;++nt) acc[nt] = (f4){0.f,0.f,0.f,0.f};
      #pragma unroll
      for (int c=0;c<4;++c){
        #pragma unroll
        for (int nt=0;nt<8;++nt){
          int o = nt*16 + l15;
          h8 bh  = *(const h8*)(W1h + (size_t)o*HH + c*32 + quad*8);
          h8 bl_ = *(const h8*)(W1l + (size_t)o*HH + c*32 + quad*8);
          acc[nt] = __builtin_amdgcn_mfma_f32_16x16x32_f16(ah[c], bh,  acc[nt], 0,0,0);
          acc[nt] = __builtin_amdgcn_mfma_f32_16x16x32_f16(al[c], bh,  acc[nt], 0,0,0);
          acc[nt] = __builtin_amdgcn_mfma_f32_16x16x32_f16(ah[c], bl_, acc[nt], 0,0,0);
          acc[nt] = __builtin_amdgcn_mfma_f32_16x16x32_f16(al[c], bl_, acc[nt], 0,0,0);
        }
      }
      float bv[8], gv[8], lv[8], wv[8];
      #pragma unroll
      for (int nt=0;nt<8;++nt){
        int o = nt*16 + l15;
        bv[nt]=b1[o]; gv[nt]=ln_g[o]; lv[nt]=ln_b[o]; wv[nt]=W2[o];
      }
      float b2v = b2[0];
      #pragma unroll
      for (int r=0;r<4;++r){
        float z[8];
        float s1=0.f, s2=0.f;
        #pragma unroll
        for (int nt=0;nt<8;++nt){
          float zz = acc[nt][r] + bv[nt];
          zz = zz>0.f ? zz : 0.f;
          z[nt] = zz; s1 += zz; s2 += zz*zz;
        }
        #pragma unroll
        for (int m=1;m<16;m<<=1){ s1 += __shfl_xor(s1,m); s2 += __shfl_xor(s2,m); }
        float mu = s1/(float)HH;
        float var = s2/(float)HH - mu*mu;
        float rs = 1.0f/sqrtf(var+EPSF);
        float s3 = 0.f;
        #pragma unroll
        for (int nt=0;nt<8;++nt){
          float zn = (z[nt]-mu)*rs*gv[nt] + lv[nt];
          s3 += zn*wv[nt];
        }
        #pragma unroll
        for (int m=1;m<16;m<<=1) s3 += __shfl_xor(s3,m);
        if (l15 == 0) llog[16*w + quad*4 + r] = s3 + b2v;
      }
      __syncthreads();
      if (t < 4){
        int n = vb*4 + t;
        float l[CCC];
        #pragma unroll
        for (int c=0;c<CCC;++c) l[c] = llog[t*16+c];
        unsigned mask = 0;
        #pragma unroll
        for (int k=0;k<KTOP;++k){
          float best = -3e38f; int bi = 0;
          #pragma unroll
          for (int c=0;c<CCC;++c){
            bool taken = (mask>>c)&1u;
            if (!taken && l[c] > best){ best = l[c]; bi = c; }
          }
          mask |= 1u<<bi;
        }
        float m = -3e38f;
        #pragma unroll
        for (int c=0;c<CCC;++c) m = l[c]>m ? l[c] : m;
        float s = 0.f;
        #pragma unroll
        for (int c=0;c<CCC;++c) s += expf(l[c]-m);
        float inv = 1.0f/s;
        unsigned m2 = mask;
        for (int j=0;j<KTOP;++j){
          int ci = __ffs(m2)-1; m2 &= m2-1u;
          unsigned rest = mask & ~(1u<<ci);
          int v[3]; unsigned r2 = rest;
          #pragma unroll
          for (int q=0;q<3;++q){ int col = __ffs(r2)-1; r2 &= r2-1u; v[q] = col - (col>ci ? 1:0); }
          int rank = C3i(v[2]) + C2i(v[1]) + v[0];
          int e4 = n*KTOP + j;
          cols[e4] = ci; ranks[e4] = rank; fiSel[e4] = expf(l[ci]-m)*inv;
        }
      }
      __syncthreads();   // protect llog before next iteration rewrites it
    }
  }
  gbar(bar);

  // ------- S2: F accumulation in LDS + nodeList/cnt build; idle blocks cvt Wl/Wr -------
  if (bid < 256){
    int cb = bid & 15, ci = bid >> 4;
    float* Ft   = SM;                 // 455*8
    int*   c455 = (int*)(SM + 3640);  // 455
    int*   lcnt = (int*)(SM + 4095);
    for (int i=t;i<NCLS*8;i+=256) Ft[i]=0.f;
    if (cb==0){
      for (int i=t;i<NCLS;i+=256) c455[i]=0;
      if (t==0) *lcnt = 0;
    }
    __syncthreads();
    for (int e=t; e<NN*KTOP; e+=256){
      if (cols[e] != ci) continue;
      int r = ranks[e]; float fi = fiSel[e]; int n = e>>2;
      const float* xr = X + ((size_t)n*CCC+ci)*HH + cb*8;
      float4 u = *(const float4*)(xr);
      float4 v = *(const float4*)(xr+4);
      atomicAdd(&Ft[r*8+0], u.x*fi); atomicAdd(&Ft[r*8+1], u.y*fi);
      atomicAdd(&Ft[r*8+2], u.z*fi); atomicAdd(&Ft[r*8+3], u.w*fi);
      atomicAdd(&Ft[r*8+4], v.x*fi); atomicAdd(&Ft[r*8+5], v.y*fi);
      atomicAdd(&Ft[r*8+6], v.z*fi); atomicAdd(&Ft[r*8+7], v.w*fi);
      if (cb==0){
        atomicAdd(&c455[r], 1);
        int pos = atomicAdd(lcnt, 1);
        nodeList[ci*NN + pos] = e;
      }
    }
    __syncthreads();
    for (int i=t;i<NCLS*8;i+=256){
      int r=i>>3, col=i&7;
      F[((size_t)ci*NCLS + r)*HH + cb*8 + col] = Ft[i];
    }
    if (cb==0){
      for (int i=t;i<NCLS;i+=256) cnt[ci*NCLS+i] = (float)c455[i];
      if (t==0) nodeCnt[ci*16] = *lcnt;
    }
  } else {
    // 128 idle blocks: convert Wl/Wr to f16 (needed first at S4/S5)
    for (int i = (bid-256)*256 + t; i < 2*262144; i += 128*256){
      if (i < 262144) hbase[HOFF_WLH + i] = (_Float16)Wl[i];
      else            hbase[HOFF_WRH + (i-262144)] = (_Float16)Wr[i-262144];
    }
  }
  gbar(bar);

  // ---------------- S3: graph pairs/singles/degrees + inclusion-exclusion agg ----------------
  if (bid < 256){
    int cb = bid & 15, ci = bid >> 4;
    float* Fl   = SM;                 // 3640
    float* P    = SM + 3640;          // 840
    float* U    = SM + 4480;          // 120
    float* cntl = SM + 4600;          // 455
    float* PcS  = SM + 5055;          // 105
    float* UcS  = SM + 5160;          // 15
    int*   abcs = (int*)(SM + 5175);  // 455
    int*   prs  = (int*)(SM + 5630);  // 455
    const float* Fc = F + (size_t)ci*NCLS*HH + cb*GCP;

    for (int i=t; i<NCLS*2; i+=256){
      int r = i>>1, hf = i&1;
      float4 v = *(const float4*)(Fc + (size_t)r*HH + hf*4);
      *(float4*)(&Fl[r*GCP + hf*4]) = v;
    }
    for (int r=t; r<NCLS; r+=256){
      cntl[r] = cnt[ci*NCLS+r];
      int c=2; while (c<14 && C3i(c+1)<=r) c++;
      int rem = r - C3i(c);
      int b=1; while (b<c-1 && C2i(b+1)<=rem) b++;
      int a = rem - C2i(b);
      abcs[r] = a | (b<<5) | (c<<10);
      prs[r] = (C2i(b)+a) | ((C2i(c)+a)<<10) | ((C2i(c)+b)<<20);
    }
    __syncthreads();
    if (t<105){
      int pb=1; while (pb<14 && C2i(pb+1)<=t) pb++;
      int pa = t - C2i(pb);
      float s=0.f;
      #pragma unroll
      for (int z=0;z<15;++z){
        if (z==pa||z==pb) continue;
        int lo,mid,hi;
        if (z<pa){lo=z;mid=pa;hi=pb;} else if (z<pb){lo=pa;mid=z;hi=pb;} else {lo=pa;mid=pb;hi=z;}
        s += cntl[C3i(hi)+C2i(mid)+lo];
      }
      PcS[t]=s;
    }
    __syncthreads();
    if (t<15){
      float s=0.f;
      #pragma unroll
      for (int y=0;y<15;++y){
        if (y==t) continue;
        int lo = t<y?t:y, hi = t<y?y:t;
        s += PcS[C2i(hi)+lo];
      }
      UcS[t]=0.5f*s;
    }
    __syncthreads();
    for (int idx=t; idx<105*GCP; idx+=256){
      int p = idx/GCP, col = idx&(GCP-1);
      int pb=1; while (pb<14 && C2i(pb+1)<=p) pb++;
      int pa = p - C2i(pb);
      float s=0.f;
      #pragma unroll
      for (int z=0;z<15;++z){
        if (z==pa||z==pb) continue;
        int lo,mid,hi;
        if (z<pa){lo=z;mid=pa;hi=pb;} else if (z<pb){lo=pa;mid=z;hi=pb;} else {lo=pa;mid=pb;hi=z;}
        s += Fl[(C3i(hi)+C2i(mid)+lo)*GCP + col];
      }
      P[idx]=s;
    }
    __syncthreads();
    for (int idx=t; idx<15*GCP; idx+=256){
      int x = idx/GCP, col = idx&(GCP-1);
      float s=0.f;
      #pragma unroll
      for (int y=0;y<15;++y){
        if (y==x) continue;
        int lo = x<y?x:y, hi = x<y?y:x;
        s += P[(C2i(hi)+lo)*GCP + col];
      }
      U[idx]=0.5f*s;
    }
    __syncthreads();
    for (int idx=t; idx<NCLS*GCP; idx+=256){
      int r = idx/GCP, col = idx&(GCP-1);
      int v1=abcs[r]; int a=v1&31,b=(v1>>5)&31,c=(v1>>10)&31;
      int v2=prs[r];  int pab=v2&1023,pac=(v2>>10)&1023,pbc=(v2>>20)&1023;
      float deg = UcS[a]+UcS[b]+UcS[c]-PcS[pab]-PcS[pac]-PcS[pbc]+cntl[r];
      float invd = 1.0f/fmaxf(deg,1.0f);
      float v = U[a*GCP+col]+U[b*GCP+col]+U[c*GCP+col]
              - P[pab*GCP+col]-P[pac*GCP+col]-P[pbc*GCP+col]
              + Fl[r*GCP+col];
      agg[(size_t)ci*NCLS*HH + (size_t)r*HH + cb*GCP + col] = v*invd;
    }
  }
  gbar(bar);

  // ---------------- S4: AggWl = Agg @ Wl^T + bl (in-place, f16 MFMA) ----------------
  if (bid < 128){
    int bx = bid & 7, ci = bid >> 3;
    int base = bx * MT;
    int rowA = base + 16*w + l15; if (rowA > NCLS-1) rowA = NCLS-1;
    const float* arow = agg + ((size_t)ci*NCLS + rowA)*HH;
    h8 af[4];
    #pragma unroll
    for (int c=0;c<4;++c){
      float4 u = *(const float4*)(arow + c*32 + quad*8);
      float4 v = *(const float4*)(arow + c*32 + quad*8 + 4);
      float xv[8] = {u.x,u.y,u.z,u.w,v.x,v.y,v.z,v.w};
      #pragma unroll
      for (int j=0;j<8;++j) af[c][j] = (_Float16)xv[j];
    }
    f4 acc[8];
    #pragma unroll
    for (int nt=0;nt<8;++nt) acc[nt] = (f4){0.f,0.f,0.f,0.f};
    const _Float16* Wc = hbase + HOFF_WLH + (size_t)ci*HH*HH;
    #pragma unroll
    for (int c=0;c<4;++c){
      #pragma unroll
      for (int nt=0;nt<8;++nt){
        int o = nt*16 + l15;
        h8 bh = *(const h8*)(Wc + (size_t)o*HH + c*32 + quad*8);
        acc[nt] = __builtin_amdgcn_mfma_f32_16x16x32_f16(af[c], bh, acc[nt], 0,0,0);
      }
    }
    #pragma unroll
    for (int r=0;r<4;++r){
      int row2 = base + 16*w + quad*4 + r;
      if (row2 < NCLS){
        float* drow = agg + ((size_t)ci*NCLS + row2)*HH;
        #pragma unroll
        for (int nt=0;nt<8;++nt){
          int o = nt*16 + l15;
          drow[o] = acc[nt][r] + bl[ci*HH + o];
        }
      }
    }
  }
  gbar(bar);

  // ---------------- S5: hc = relu(AggWl[class] + fi*X @ Wr^T) ----------------
  {
    float* rb = SM;  // 8 floats
    for (int vb = bid; vb < 48*16; vb += GRID){
      int ci = vb & 15, bx = vb >> 4;
      int cntc = nodeCnt[ci*16];
      int base = bx * MT;
      __syncthreads();            // protect rb reuse across iterations (uniform path)
      if (base >= cntc) continue; // block-uniform
      int pA = base + 16*w + l15;
      float fi = 0.f; int nA = 0;
      if (pA < cntc){
        int e = nodeList[ci*NN + pA];
        fi = fiSel[e]; nA = e >> 2;
      }
      const float* xrow = X + ((size_t)nA*CCC + ci)*HH;
      h8 af[4];
      #pragma unroll
      for (int c=0;c<4;++c){
        float4 u = *(const float4*)(xrow + c*32 + quad*8);
        float4 v = *(const float4*)(xrow + c*32 + quad*8 + 4);
        float xv[8] = {u.x,u.y,u.z,u.w,v.x,v.y,v.z,v.w};
        #pragma unroll
        for (int j=0;j<8;++j) af[c][j] = (_Float16)(xv[j]*fi);
      }
      f4 acc[8];
      #pragma unroll
      for (int nt=0;nt<8;++nt) acc[nt] = (f4){0.f,0.f,0.f,0.f};
      const _Float16* Wc = hbase + HOFF_WRH + (size_t)ci*HH*HH;
      #pragma unroll
      for (int c=0;c<4;++c){
        #pragma unroll
        for (int nt=0;nt<8;++nt){
          int o = nt*16 + l15;
          h8 bh = *(const h8*)(Wc + (size_t)o*HH + c*32 + quad*8);
          acc[nt] = __builtin_amdgcn_mfma_f32_16x16x32_f16(af[c], bh, acc[nt], 0,0,0);
        }
      }
      float s1 = 0.f, s2 = 0.f;
      #pragma unroll
      for (int r=0;r<4;++r){
        int pD = base + 16*w + quad*4 + r;
        int e2 = -1, rk2 = 0;
        if (pD < cntc){ e2 = nodeList[ci*NN + pD]; rk2 = ranks[e2]; }
        if (e2 >= 0){
          const float* G = agg + ((size_t)ci*NCLS + rk2)*HH;
          float* drow = hcBuf + (size_t)e2*HH;
          #pragma unroll
          for (int nt=0;nt<8;++nt){
            int o = nt*16 + l15;
            float vv = acc[nt][r] + G[o];
            vv = vv>0.f ? vv : 0.f;
            drow[o] = vv;
            s1 += vv; s2 += vv*vv;
          }
        }
      }
      #pragma unroll
      for (int m=1;m<64;m<<=1){ s1 += __shfl_xor(s1,m); s2 += __shfl_xor(s2,m); }
      if (lane == 0){ rb[w] = s1; rb[4+w] = s2; }
      __syncthreads();
      if (t==0){
        atomicAdd(&sums[ci],    rb[0]+rb[1]+rb[2]+rb[3]);
        atomicAdd(&sums[16+ci], rb[4]+rb[5]+rb[6]+rb[7]);
      }
    }
  }
  gbar(bar);

  // ---------------- S6: masked mean/var normalize, write output ----------------
  {
    const int TOT4 = NN*KTOP*HH/4;
    for (int i4 = bid*256 + t; i4 < TOT4; i4 += GRID*256){
      int e = i4 >> 5;               // 32 float4 per 128-wide row
      int ci = cols[e];
      float cntf = (float)nodeCnt[ci*16];
      float nel = fmaxf(cntf * (float)HH, 1.0f);
      float mu = sums[ci]/nel;
      float var = sums[16+ci]/nel - mu*mu;
      float sq = sqrtf(var+EPSF);
      float4 hv = *(const float4*)(hcBuf + (size_t)i4*4);
      float4 ov;
      ov.x = (hv.x-mu)/sq; ov.y = (hv.y-mu)/sq;
      ov.z = (hv.z-mu)/sq; ov.w = (hv.w-mu)/sq;
      *(float4*)(out + (size_t)i4*4) = ov;
    }
  }
}

extern "C" void kernel_launch(void* const* d_in, const int* in_sizes, int n_in,
                              void* d_out, int out_size, void* d_ws, size_t ws_size,
                              hipStream_t stream){
  const float* X    = (const float*)d_in[0];
  const float* W1   = (const float*)d_in[1];
  const float* b1   = (const float*)d_in[2];
  const float* ln_g = (const float*)d_in[3];
  const float* ln_b = (const float*)d_in[4];
  const float* W2   = (const float*)d_in[5];
  const float* b2   = (const float*)d_in[6];
  const float* Wl   = (const float*)d_in[7];
  const float* bl   = (const float*)d_in[8];
  const float* Wr   = (const float*)d_in[9];
  float* ws  = (float*)d_ws;
  float* outp = (float*)d_out;

  k_init <<<dim3(1), dim3(64), 0, stream>>>(ws);
  k_mega <<<dim3(GRID), dim3(256), 0, stream>>>(X, W1, b1, ln_g, ln_b, W2, b2,
                                                Wl, bl, Wr, ws, outp);
}

// Round 8
// 375.419 us; speedup vs baseline: 1.5624x; 1.5624x over previous
//
#include <hip/hip_runtime.h>

#define NN 3072
#define CCC 16
#define HH 128
#define KTOP 4
#define NCLS 455   // C(15,3)
#define EPSF 1e-5f

// ---------------- ws layout (float offsets) ----------------
#define OFF_F       0
#define SZ_F        (16*NCLS*HH)            // 931840
#define OFF_CNT     (OFF_F + SZ_F)
#define SZ_CNT      (16*NCLS)
#define OFF_SUMS    (OFF_CNT + SZ_CNT)
#define SZ_SUMS     32
#define OFF_NCNT    (OFF_SUMS + SZ_SUMS)    // int nodeCnt[16*16]
#define SZ_NCNT     256
#define ZERO_END    (OFF_NCNT + SZ_NCNT)    // S0 zeroes ws[0..ZERO_END)
#define OFF_BAR     ZERO_END                // int bar: monotonic arrival counter
#define SZ_BAR      64
#define OFF_COLS    (OFF_BAR + SZ_BAR)
#define SZ_E        (NN*KTOP)
#define OFF_RANKS   (OFF_COLS + SZ_E)
#define OFF_FISEL   (OFF_RANKS + SZ_E)
#define OFF_NLIST   (OFF_FISEL + SZ_E)
#define SZ_NLIST    (16*NN)
#define OFF_AGG     (OFF_NLIST + SZ_NLIST)
#define OFF_HC      (OFF_AGG + SZ_F)
#define SZ_HC       (NN*KTOP*HH)
#define OFF_HALF    (OFF_HC + SZ_HC)
#define HOFF_W1H    0
#define HOFF_W1L    16384
#define HOFF_WLH    32768
#define HOFF_WRH    (32768 + 262144)
#define CVT_TOTAL   (16384 + 262144 + 262144)

#define GRID 384   // R6-proven co-resident at 24KB LDS / launch_bounds(256,2)
#define MT 64
#define GCP 8

typedef _Float16 h8 __attribute__((ext_vector_type(8)));
typedef float    f4 __attribute__((ext_vector_type(4)));

__device__ __forceinline__ int C2i(int x){ return x*(x-1)/2; }
__device__ __forceinline__ int C3i(int x){ return x*(x-1)*(x-2)/6; }

// ---- device barrier: RELAXED fetch_add(0) polling (RMW reads at coherence point,
// no per-poll cache invalidate); one RELEASE on arrival, one ACQUIRE at exit.
// Monotonic counter: barrier k waits for cnt >= k*GRID (no reset race).
__device__ __forceinline__ void gbar(int* bar, int target){
  __syncthreads();
  if (threadIdx.x == 0){
    __hip_atomic_fetch_add(bar, 1, __ATOMIC_RELEASE, __HIP_MEMORY_SCOPE_AGENT);
    while (__hip_atomic_fetch_add(bar, 0, __ATOMIC_RELAXED, __HIP_MEMORY_SCOPE_AGENT) < target)
      __builtin_amdgcn_s_sleep(32);
    (void)__hip_atomic_load(bar, __ATOMIC_ACQUIRE, __HIP_MEMORY_SCOPE_AGENT);
  }
  __syncthreads();
}

// -------- init: zero barrier counter (ws re-poisoned between iterations) --------
__global__ __launch_bounds__(64) void k_init(float* __restrict__ ws){
  if (threadIdx.x < 16) ((int*)(ws + OFF_BAR))[threadIdx.x] = 0;
}

// ================== ONE mega-kernel: 7 stages, 6 device barriers ==================
__global__ __launch_bounds__(256, 2) void k_mega(
    const float* __restrict__ X,  const float* __restrict__ W1,
    const float* __restrict__ b1, const float* __restrict__ ln_g,
    const float* __restrict__ ln_b,const float* __restrict__ W2,
    const float* __restrict__ b2, const float* __restrict__ Wl,
    const float* __restrict__ bl, const float* __restrict__ Wr,
    float* __restrict__ ws, float* __restrict__ out)
{
  __shared__ __align__(16) float SM[6144];   // 24 KB union, re-aliased per stage
  int t = threadIdx.x;
  int bid = blockIdx.x;
  int w = t >> 6;
  int lane = t & 63;
  int l15 = lane & 15, quad = lane >> 4;

  float* F      = ws + OFF_F;
  float* cnt    = ws + OFF_CNT;
  float* sums   = ws + OFF_SUMS;
  int*   nodeCnt= (int*)(ws + OFF_NCNT);
  int*   bar    = (int*)(ws + OFF_BAR);
  int*   cols   = (int*)(ws + OFF_COLS);
  int*   ranks  = (int*)(ws + OFF_RANKS);
  float* fiSel  = ws + OFF_FISEL;
  int*   nodeList=(int*)(ws + OFF_NLIST);
  float* agg    = ws + OFF_AGG;
  float* hcBuf  = ws + OFF_HC;
  _Float16* hbase = (_Float16*)(ws + OFF_HALF);

  // ---- S0: zero F/cnt/sums/nodeCnt + cvt W1 (hi/lo) + cvt Wl/Wr, grid-strided ----
  {
    for (int i = bid*256 + t; i < ZERO_END; i += GRID*256) ws[i] = 0.f;
    for (int i = bid*256 + t; i < CVT_TOTAL; i += GRID*256){
      if (i < 16384){
        float x = W1[i];
        _Float16 h = (_Float16)x;
        hbase[HOFF_W1H + i] = h;
        hbase[HOFF_W1L + i] = (_Float16)(x - (float)h);
      } else if (i < 16384 + 262144){
        hbase[HOFF_WLH + (i - 16384)] = (_Float16)Wl[i - 16384];
      } else {
        hbase[HOFF_WRH + (i - 16384 - 262144)] = (_Float16)Wr[i - 16384 - 262144];
      }
    }
  }
  gbar(bar, 1*GRID);

  // ---------------- S1: logits (MFMA hi/lo) -> in-LDS topk/softmax ----------------
  {
    const _Float16* W1h = hbase + HOFF_W1H;
    const _Float16* W1l = hbase + HOFF_W1L;
    float* llog = SM;   // 64 floats
    for (int vb = bid; vb < NN*CCC/MT; vb += GRID){
      int base = vb * MT;
      int mA = base + 16*w + l15;
      const float* xrow = X + (size_t)mA*HH;
      h8 ah[4], al[4];
      #pragma unroll
      for (int c=0;c<4;++c){
        float4 u = *(const float4*)(xrow + c*32 + quad*8);
        float4 v = *(const float4*)(xrow + c*32 + quad*8 + 4);
        float xv[8] = {u.x,u.y,u.z,u.w,v.x,v.y,v.z,v.w};
        #pragma unroll
        for (int j=0;j<8;++j){
          _Float16 hi = (_Float16)xv[j];
          ah[c][j] = hi;
          al[c][j] = (_Float16)(xv[j] - (float)hi);
        }
      }
      f4 acc[8];
      #pragma unroll
      for (int nt=0;nt<8;++nt) acc[nt] = (f4){0.f,0.f,0.f,0.f};
      #pragma unroll
      for (int c=0;c<4;++c){
        #pragma unroll
        for (int nt=0;nt<8;++nt){
          int o = nt*16 + l15;
          h8 bh  = *(const h8*)(W1h + (size_t)o*HH + c*32 + quad*8);
          h8 bl_ = *(const h8*)(W1l + (size_t)o*HH + c*32 + quad*8);
          acc[nt] = __builtin_amdgcn_mfma_f32_16x16x32_f16(ah[c], bh,  acc[nt], 0,0,0);
          acc[nt] = __builtin_amdgcn_mfma_f32_16x16x32_f16(al[c], bh,  acc[nt], 0,0,0);
          acc[nt] = __builtin_amdgcn_mfma_f32_16x16x32_f16(ah[c], bl_, acc[nt], 0,0,0);
          acc[nt] = __builtin_amdgcn_mfma_f32_16x16x32_f16(al[c], bl_, acc[nt], 0,0,0);
        }
      }
      float bv[8], gv[8], lv[8], wv[8];
      #pragma unroll
      for (int nt=0;nt<8;++nt){
        int o = nt*16 + l15;
        bv[nt]=b1[o]; gv[nt]=ln_g[o]; lv[nt]=ln_b[o]; wv[nt]=W2[o];
      }
      float b2v = b2[0];
      #pragma unroll
      for (int r=0;r<4;++r){
        float z[8];
        float s1=0.f, s2=0.f;
        #pragma unroll
        for (int nt=0;nt<8;++nt){
          float zz = acc[nt][r] + bv[nt];
          zz = zz>0.f ? zz : 0.f;
          z[nt] = zz; s1 += zz; s2 += zz*zz;
        }
        #pragma unroll
        for (int m=1;m<16;m<<=1){ s1 += __shfl_xor(s1,m); s2 += __shfl_xor(s2,m); }
        float mu = s1/(float)HH;
        float var = s2/(float)HH - mu*mu;
        float rs = 1.0f/sqrtf(var+EPSF);
        float s3 = 0.f;
        #pragma unroll
        for (int nt=0;nt<8;++nt){
          float zn = (z[nt]-mu)*rs*gv[nt] + lv[nt];
          s3 += zn*wv[nt];
        }
        #pragma unroll
        for (int m=1;m<16;m<<=1) s3 += __shfl_xor(s3,m);
        if (l15 == 0) llog[16*w + quad*4 + r] = s3 + b2v;
      }
      __syncthreads();
      if (t < 4){
        int n = vb*4 + t;
        float l[CCC];
        #pragma unroll
        for (int c=0;c<CCC;++c) l[c] = llog[t*16+c];
        unsigned mask = 0;
        #pragma unroll
        for (int k=0;k<KTOP;++k){
          float best = -3e38f; int bi = 0;
          #pragma unroll
          for (int c=0;c<CCC;++c){
            bool taken = (mask>>c)&1u;
            if (!taken && l[c] > best){ best = l[c]; bi = c; }
          }
          mask |= 1u<<bi;
        }
        float m = -3e38f;
        #pragma unroll
        for (int c=0;c<CCC;++c) m = l[c]>m ? l[c] : m;
        float s = 0.f;
        #pragma unroll
        for (int c=0;c<CCC;++c) s += expf(l[c]-m);
        float inv = 1.0f/s;
        unsigned m2 = mask;
        for (int j=0;j<KTOP;++j){
          int ci = __ffs(m2)-1; m2 &= m2-1u;
          unsigned rest = mask & ~(1u<<ci);
          int v[3]; unsigned r2 = rest;
          #pragma unroll
          for (int q=0;q<3;++q){ int col = __ffs(r2)-1; r2 &= r2-1u; v[q] = col - (col>ci ? 1:0); }
          int rank = C3i(v[2]) + C2i(v[1]) + v[0];
          int e4 = n*KTOP + j;
          cols[e4] = ci; ranks[e4] = rank; fiSel[e4] = expf(l[ci]-m)*inv;
        }
      }
      __syncthreads();   // protect llog before next iteration rewrites it
    }
  }
  gbar(bar, 2*GRID);

  // ---- S2: F accumulation via high-TLP fire-and-forget atomics (R1-proven path);
  // ----     blocks 0..11 build nodeList/nodeCnt with LDS batching (k_nlist logic)
  if (bid < 12){
    int* lcnt  = (int*)SM;        // 16
    int* lbase = (int*)SM + 16;   // 16
    if (t < CCC) lcnt[t] = 0;
    __syncthreads();
    int n = bid*256 + t;
    int mycis[KTOP], mypos[KTOP];
    #pragma unroll
    for (int j=0;j<KTOP;++j){
      int ci = cols[n*KTOP+j];
      mycis[j] = ci;
      mypos[j] = atomicAdd(&lcnt[ci], 1);
    }
    __syncthreads();
    if (t < CCC) lbase[t] = atomicAdd(&nodeCnt[t*16], lcnt[t]);
    __syncthreads();
    #pragma unroll
    for (int j=0;j<KTOP;++j){
      int ci = mycis[j];
      nodeList[ci*NN + lbase[ci] + mypos[j]] = n*KTOP + j;
    }
  } else {
    // (edge, col-group) grid-stride: 12288 edges x 16 groups of 8 cols
    for (int i = (bid-12)*256 + t; i < NN*KTOP*16; i += (GRID-12)*256){
      int e = i >> 4, cg = i & 15;
      int ci = cols[e], r = ranks[e];
      float fi = fiSel[e];
      int n = e >> 2;
      const float* xr = X + ((size_t)n*CCC + ci)*HH + cg*8;
      float4 u = *(const float4*)(xr);
      float4 v = *(const float4*)(xr+4);
      float* Fr = F + ((size_t)ci*NCLS + r)*HH + cg*8;
      atomicAdd(&Fr[0], u.x*fi); atomicAdd(&Fr[1], u.y*fi);
      atomicAdd(&Fr[2], u.z*fi); atomicAdd(&Fr[3], u.w*fi);
      atomicAdd(&Fr[4], v.x*fi); atomicAdd(&Fr[5], v.y*fi);
      atomicAdd(&Fr[6], v.z*fi); atomicAdd(&Fr[7], v.w*fi);
      if (cg == 0) atomicAdd(&cnt[ci*NCLS + r], 1.0f);
    }
  }
  gbar(bar, 3*GRID);

  // ---- S3: graph pairs/singles/degrees + inclusion-exclusion agg (GCP=8, 256 vb) ----
  if (bid < 256){
    int cb = bid & 15, ci = bid >> 4;
    float* Fl   = SM;                 // 3640
    float* P    = SM + 3640;          // 840
    float* U    = SM + 4480;          // 120
    float* cntl = SM + 4600;          // 455
    float* PcS  = SM + 5055;          // 105
    float* UcS  = SM + 5160;          // 15
    int*   abcs = (int*)(SM + 5175);  // 455
    int*   prs  = (int*)(SM + 5630);  // 455
    const float* Fc = F + (size_t)ci*NCLS*HH + cb*GCP;

    for (int i=t; i<NCLS*2; i+=256){
      int r = i>>1, hf = i&1;
      float4 v = *(const float4*)(Fc + (size_t)r*HH + hf*4);
      *(float4*)(&Fl[r*GCP + hf*4]) = v;
    }
    for (int r=t; r<NCLS; r+=256){
      cntl[r] = cnt[ci*NCLS+r];
      int c=2; while (c<14 && C3i(c+1)<=r) c++;
      int rem = r - C3i(c);
      int b=1; while (b<c-1 && C2i(b+1)<=rem) b++;
      int a = rem - C2i(b);
      abcs[r] = a | (b<<5) | (c<<10);
      prs[r] = (C2i(b)+a) | ((C2i(c)+a)<<10) | ((C2i(c)+b)<<20);
    }
    __syncthreads();
    if (t<105){
      int pb=1; while (pb<14 && C2i(pb+1)<=t) pb++;
      int pa = t - C2i(pb);
      float s=0.f;
      #pragma unroll
      for (int z=0;z<15;++z){
        if (z==pa||z==pb) continue;
        int lo,mid,hi;
        if (z<pa){lo=z;mid=pa;hi=pb;} else if (z<pb){lo=pa;mid=z;hi=pb;} else {lo=pa;mid=pb;hi=z;}
        s += cntl[C3i(hi)+C2i(mid)+lo];
      }
      PcS[t]=s;
    }
    __syncthreads();
    if (t<15){
      float s=0.f;
      #pragma unroll
      for (int y=0;y<15;++y){
        if (y==t) continue;
        int lo = t<y?t:y, hi = t<y?y:t;
        s += PcS[C2i(hi)+lo];
      }
      UcS[t]=0.5f*s;
    }
    __syncthreads();
    for (int idx=t; idx<105*GCP; idx+=256){
      int p = idx/GCP, col = idx&(GCP-1);
      int pb=1; while (pb<14 && C2i(pb+1)<=p) pb++;
      int pa = p - C2i(pb);
      float s=0.f;
      #pragma unroll
      for (int z=0;z<15;++z){
        if (z==pa||z==pb) continue;
        int lo,mid,hi;
        if (z<pa){lo=z;mid=pa;hi=pb;} else if (z<pb){lo=pa;mid=z;hi=pb;} else {lo=pa;mid=pb;hi=z;}
        s += Fl[(C3i(hi)+C2i(mid)+lo)*GCP + col];
      }
      P[idx]=s;
    }
    __syncthreads();
    for (int idx=t; idx<15*GCP; idx+=256){
      int x = idx/GCP, col = idx&(GCP-1);
      float s=0.f;
      #pragma unroll
      for (int y=0;y<15;++y){
        if (y==x) continue;
        int lo = x<y?x:y, hi = x<y?y:x;
        s += P[(C2i(hi)+lo)*GCP + col];
      }
      U[idx]=0.5f*s;
    }
    __syncthreads();
    for (int idx=t; idx<NCLS*GCP; idx+=256){
      int r = idx/GCP, col = idx&(GCP-1);
      int v1=abcs[r]; int a=v1&31,b=(v1>>5)&31,c=(v1>>10)&31;
      int v2=prs[r];  int pab=v2&1023,pac=(v2>>10)&1023,pbc=(v2>>20)&1023;
      float deg = UcS[a]+UcS[b]+UcS[c]-PcS[pab]-PcS[pac]-PcS[pbc]+cntl[r];
      float invd = 1.0f/fmaxf(deg,1.0f);
      float v = U[a*GCP+col]+U[b*GCP+col]+U[c*GCP+col]
              - P[pab*GCP+col]-P[pac*GCP+col]-P[pbc*GCP+col]
              + Fl[r*GCP+col];
      agg[(size_t)ci*NCLS*HH + (size_t)r*HH + cb*GCP + col] = v*invd;
    }
  }
  gbar(bar, 4*GRID);

  // ---- S4: AggWl = Agg @ Wl^T + bl (in-place, f16 MFMA) ----
  // EXCLUSIVE ownership (R6-proven race-free): each of 128 blocks owns 64 rows of one
  // class, reads its full rows then writes its full rows. No cross-block row sharing.
  if (bid < 128){
    int bx = bid & 7, ci = bid >> 3;
    int base = bx * MT;
    int rowA = base + 16*w + l15; if (rowA > NCLS-1) rowA = NCLS-1;
    const float* arow = agg + ((size_t)ci*NCLS + rowA)*HH;
    h8 af[4];
    #pragma unroll
    for (int c=0;c<4;++c){
      float4 u = *(const float4*)(arow + c*32 + quad*8);
      float4 v = *(const float4*)(arow + c*32 + quad*8 + 4);
      float xv[8] = {u.x,u.y,u.z,u.w,v.x,v.y,v.z,v.w};
      #pragma unroll
      for (int j=0;j<8;++j) af[c][j] = (_Float16)xv[j];
    }
    f4 acc[8];
    #pragma unroll
    for (int nt=0;nt<8;++nt) acc[nt] = (f4){0.f,0.f,0.f,0.f};
    const _Float16* Wc = hbase + HOFF_WLH + (size_t)ci*HH*HH;
    #pragma unroll
    for (int c=0;c<4;++c){
      #pragma unroll
      for (int nt=0;nt<8;++nt){
        int o = nt*16 + l15;
        h8 bh = *(const h8*)(Wc + (size_t)o*HH + c*32 + quad*8);
        acc[nt] = __builtin_amdgcn_mfma_f32_16x16x32_f16(af[c], bh, acc[nt], 0,0,0);
      }
    }
    #pragma unroll
    for (int r=0;r<4;++r){
      int row2 = base + 16*w + quad*4 + r;
      if (row2 < NCLS){
        float* drow = agg + ((size_t)ci*NCLS + row2)*HH;
        #pragma unroll
        for (int nt=0;nt<8;++nt){
          int o = nt*16 + l15;
          drow[o] = acc[nt][r] + bl[ci*HH + o];
        }
      }
    }
  }
  gbar(bar, 5*GRID);

  // ---------------- S5: hc = relu(AggWl[class] + fi*X @ Wr^T) ----------------
  {
    float* rb = SM;  // 8 floats
    for (int vb = bid; vb < 48*16; vb += GRID){
      int ci = vb & 15, bx = vb >> 4;
      int cntc = nodeCnt[ci*16];
      int base = bx * MT;
      __syncthreads();            // protect rb reuse across iterations (uniform path)
      if (base >= cntc) continue; // block-uniform
      int pA = base + 16*w + l15;
      float fi = 0.f; int nA = 0;
      if (pA < cntc){
        int e = nodeList[ci*NN + pA];
        fi = fiSel[e]; nA = e >> 2;
      }
      const float* xrow = X + ((size_t)nA*CCC + ci)*HH;
      h8 af[4];
      #pragma unroll
      for (int c=0;c<4;++c){
        float4 u = *(const float4*)(xrow + c*32 + quad*8);
        float4 v = *(const float4*)(xrow + c*32 + quad*8 + 4);
        float xv[8] = {u.x,u.y,u.z,u.w,v.x,v.y,v.z,v.w};
        #pragma unroll
        for (int j=0;j<8;++j) af[c][j] = (_Float16)(xv[j]*fi);
      }
      f4 acc[8];
      #pragma unroll
      for (int nt=0;nt<8;++nt) acc[nt] = (f4){0.f,0.f,0.f,0.f};
      const _Float16* Wc = hbase + HOFF_WRH + (size_t)ci*HH*HH;
      #pragma unroll
      for (int c=0;c<4;++c){
        #pragma unroll
        for (int nt=0;nt<8;++nt){
          int o = nt*16 + l15;
          h8 bh = *(const h8*)(Wc + (size_t)o*HH + c*32 + quad*8);
          acc[nt] = __builtin_amdgcn_mfma_f32_16x16x32_f16(af[c], bh, acc[nt], 0,0,0);
        }
      }
      float s1 = 0.f, s2 = 0.f;
      #pragma unroll
      for (int r=0;r<4;++r){
        int pD = base + 16*w + quad*4 + r;
        int e2 = -1, rk2 = 0;
        if (pD < cntc){ e2 = nodeList[ci*NN + pD]; rk2 = ranks[e2]; }
        if (e2 >= 0){
          const float* G = agg + ((size_t)ci*NCLS + rk2)*HH;
          float* drow = hcBuf + (size_t)e2*HH;
          #pragma unroll
          for (int nt=0;nt<8;++nt){
            int o = nt*16 + l15;
            float vv = acc[nt][r] + G[o];
            vv = vv>0.f ? vv : 0.f;
            drow[o] = vv;
            s1 += vv; s2 += vv*vv;
          }
        }
      }
      #pragma unroll
      for (int m=1;m<64;m<<=1){ s1 += __shfl_xor(s1,m); s2 += __shfl_xor(s2,m); }
      if (lane == 0){ rb[w] = s1; rb[4+w] = s2; }
      __syncthreads();
      if (t==0){
        atomicAdd(&sums[ci],    rb[0]+rb[1]+rb[2]+rb[3]);
        atomicAdd(&sums[16+ci], rb[4]+rb[5]+rb[6]+rb[7]);
      }
    }
  }
  gbar(bar, 6*GRID);

  // ---------------- S6: masked mean/var normalize, write output ----------------
  {
    const int TOT4 = NN*KTOP*HH/4;
    for (int i4 = bid*256 + t; i4 < TOT4; i4 += GRID*256){
      int e = i4 >> 5;               // 32 float4 per 128-wide row
      int ci = cols[e];
      float cntf = (float)nodeCnt[ci*16];
      float nel = fmaxf(cntf * (float)HH, 1.0f);
      float mu = sums[ci]/nel;
      float var = sums[16+ci]/nel - mu*mu;
      float sq = sqrtf(var+EPSF);
      float4 hv = *(const float4*)(hcBuf + (size_t)i4*4);
      float4 ov;
      ov.x = (hv.x-mu)/sq; ov.y = (hv.y-mu)/sq;
      ov.z = (hv.z-mu)/sq; ov.w = (hv.w-mu)/sq;
      *(float4*)(out + (size_t)i4*4) = ov;
    }
  }
}

extern "C" void kernel_launch(void* const* d_in, const int* in_sizes, int n_in,
                              void* d_out, int out_size, void* d_ws, size_t ws_size,
                              hipStream_t stream){
  const float* X    = (const float*)d_in[0];
  const float* W1   = (const float*)d_in[1];
  const float* b1   = (const float*)d_in[2];
  const float* ln_g = (const float*)d_in[3];
  const float* ln_b = (const float*)d_in[4];
  const float* W2   = (const float*)d_in[5];
  const float* b2   = (const float*)d_in[6];
  const float* Wl   = (const float*)d_in[7];
  const float* bl   = (const float*)d_in[8];
  const float* Wr   = (const float*)d_in[9];
  float* ws  = (float*)d_ws;
  float* outp = (float*)d_out;

  k_init <<<dim3(1), dim3(64), 0, stream>>>(ws);
  k_mega <<<dim3(GRID), dim3(256), 0, stream>>>(X, W1, b1, ln_g, ln_b, W2, b2,
                                                Wl, bl, Wr, ws, outp);
}

// Round 9
// 175.499 us; speedup vs baseline: 3.3422x; 2.1391x over previous
//
#include <hip/hip_runtime.h>

#define NN 3072
#define CCC 16
#define HH 128
#define KTOP 4
#define NCLS 455   // C(15,3)
#define EPSF 1e-5f

// ---------------- ws layout (float offsets) ----------------
#define OFF_F       0
#define SZ_F        (16*NCLS*HH)            // 931840
#define OFF_CNT     (OFF_F + SZ_F)
#define SZ_CNT      (16*NCLS)
#define OFF_SUMS    (OFF_CNT + SZ_CNT)
#define SZ_SUMS     32
#define OFF_NCNT    (OFF_SUMS + SZ_SUMS)    // int nodeCnt[16*16]
#define SZ_NCNT     256
#define SMALL_ZERO  (SZ_CNT + SZ_SUMS + SZ_NCNT)  // cnt+sums+nodeCnt zeroed by k_cvt
#define OFF_COLS    (OFF_NCNT + SZ_NCNT)
#define SZ_E        (NN*KTOP)
#define OFF_RANKS   (OFF_COLS + SZ_E)
#define OFF_FISEL   (OFF_RANKS + SZ_E)
#define OFF_NLIST   (OFF_FISEL + SZ_E)
#define SZ_NLIST    (16*NN)
#define OFF_AGG     (OFF_NLIST + SZ_NLIST)
#define OFF_HC      (OFF_AGG + SZ_F)
#define SZ_HC       (NN*KTOP*HH)
#define OFF_HALF    (OFF_HC + SZ_HC)
#define HOFF_W1H    0
#define HOFF_W1L    16384
#define HOFF_WLH    32768
#define HOFF_WRH    (32768 + 262144)

#define MT 64
#define GCP 8              // k_graph cols per block
#define GCB (HH/GCP)

typedef _Float16 h8 __attribute__((ext_vector_type(8)));
typedef float    f4 __attribute__((ext_vector_type(4)));

__device__ __forceinline__ int C2i(int x){ return x*(x-1)/2; }
__device__ __forceinline__ int C3i(int x){ return x*(x-1)*(x-2)/6; }

// ======== stage 0 (small): W1 -> f16 hi/lo + zero cnt/sums/nodeCnt ========
__global__ __launch_bounds__(256) void k_cvt(const float* __restrict__ W1,
    _Float16* __restrict__ hbase, float* __restrict__ ws){
  int i = blockIdx.x*256 + threadIdx.x;
  if (i < 16384){
    float x = W1[i];
    _Float16 h = (_Float16)x;
    hbase[HOFF_W1H + i] = h;
    hbase[HOFF_W1L + i] = (_Float16)(x - (float)h);
  }
  if (i < SMALL_ZERO) ws[OFF_CNT + i] = 0.f;
}

// ===== stage A+B fused: logits (MFMA hi/lo) -> in-LDS topk/softmax (R4-proven) =====
// Folded in (independent, overlapped): F zeroing + Wl/Wr f16 conversion.
__global__ __launch_bounds__(256) void k_fused(const float* __restrict__ X,
    const _Float16* __restrict__ W1h, const _Float16* __restrict__ W1l,
    const float* __restrict__ b1, const float* __restrict__ ln_g,
    const float* __restrict__ ln_b, const float* __restrict__ W2,
    const float* __restrict__ b2,
    const float* __restrict__ Wl, const float* __restrict__ Wr,
    _Float16* __restrict__ hbase, float* __restrict__ F,
    int* __restrict__ cols, int* __restrict__ ranks, float* __restrict__ fiSel){
  __shared__ float llog[64];
  int t = threadIdx.x;
  int w = t >> 6;
  int lane = t & 63;
  int l15 = lane & 15, quad = lane >> 4;
  int base = blockIdx.x * MT;
  int mA = base + 16*w + l15;

  // ---- folded housekeeping: zero F (float4 grid-stride) + cvt Wl/Wr ----
  {
    f4 z4 = (f4){0.f,0.f,0.f,0.f};
    for (int i = blockIdx.x*256 + t; i < SZ_F/4; i += 768*256)
      *(f4*)(F + (size_t)i*4) = z4;
    for (int i = blockIdx.x*256 + t; i < 2*262144; i += 768*256){
      if (i < 262144) hbase[HOFF_WLH + i] = (_Float16)Wl[i];
      else            hbase[HOFF_WRH + (i-262144)] = (_Float16)Wr[i-262144];
    }
  }

  // ---- phase 1: z=relu(X@W1^T+b1); LN; logit=zn.W2+b2 (identical math) ----
  const float* xrow = X + (size_t)mA*HH;
  h8 ah[4], al[4];
  #pragma unroll
  for (int c=0;c<4;++c){
    float4 u = *(const float4*)(xrow + c*32 + quad*8);
    float4 v = *(const float4*)(xrow + c*32 + quad*8 + 4);
    float xv[8] = {u.x,u.y,u.z,u.w,v.x,v.y,v.z,v.w};
    #pragma unroll
    for (int j=0;j<8;++j){
      _Float16 hi = (_Float16)xv[j];
      ah[c][j] = hi;
      al[c][j] = (_Float16)(xv[j] - (float)hi);
    }
  }

  f4 acc[8];
  #pragma unroll
  for (int nt=0;nt<8;++nt) acc[nt] = (f4){0.f,0.f,0.f,0.f};

  #pragma unroll
  for (int c=0;c<4;++c){
    #pragma unroll
    for (int nt=0;nt<8;++nt){
      int o = nt*16 + l15;
      h8 bh  = *(const h8*)(W1h + (size_t)o*HH + c*32 + quad*8);
      h8 bl_ = *(const h8*)(W1l + (size_t)o*HH + c*32 + quad*8);
      acc[nt] = __builtin_amdgcn_mfma_f32_16x16x32_f16(ah[c], bh,  acc[nt], 0,0,0);
      acc[nt] = __builtin_amdgcn_mfma_f32_16x16x32_f16(al[c], bh,  acc[nt], 0,0,0);
      acc[nt] = __builtin_amdgcn_mfma_f32_16x16x32_f16(ah[c], bl_, acc[nt], 0,0,0);
      acc[nt] = __builtin_amdgcn_mfma_f32_16x16x32_f16(al[c], bl_, acc[nt], 0,0,0);
    }
  }

  float bv[8], gv[8], lv[8], wv[8];
  #pragma unroll
  for (int nt=0;nt<8;++nt){
    int o = nt*16 + l15;
    bv[nt]=b1[o]; gv[nt]=ln_g[o]; lv[nt]=ln_b[o]; wv[nt]=W2[o];
  }
  float b2v = b2[0];
  #pragma unroll
  for (int r=0;r<4;++r){
    float z[8];
    float s1=0.f, s2=0.f;
    #pragma unroll
    for (int nt=0;nt<8;++nt){
      float zz = acc[nt][r] + bv[nt];
      zz = zz>0.f ? zz : 0.f;
      z[nt] = zz; s1 += zz; s2 += zz*zz;
    }
    #pragma unroll
    for (int m=1;m<16;m<<=1){ s1 += __shfl_xor(s1,m); s2 += __shfl_xor(s2,m); }
    float mu = s1/(float)HH;
    float var = s2/(float)HH - mu*mu;
    float rs = 1.0f/sqrtf(var+EPSF);
    float s3 = 0.f;
    #pragma unroll
    for (int nt=0;nt<8;++nt){
      float zn = (z[nt]-mu)*rs*gv[nt] + lv[nt];
      s3 += zn*wv[nt];
    }
    #pragma unroll
    for (int m=1;m<16;m<<=1) s3 += __shfl_xor(s3,m);
    if (l15 == 0) llog[16*w + quad*4 + r] = s3 + b2v;
  }
  __syncthreads();

  // ---- phase 2: topk/softmax per node (threads 0..3), plain stores only ----
  if (t < 4){
    int n = blockIdx.x*4 + t;
    float l[CCC];
    #pragma unroll
    for (int c=0;c<CCC;++c) l[c] = llog[t*16+c];
    unsigned mask = 0;
    #pragma unroll
    for (int k=0;k<KTOP;++k){
      float best = -3e38f; int bi = 0;
      #pragma unroll
      for (int c=0;c<CCC;++c){
        bool taken = (mask>>c)&1u;
        if (!taken && l[c] > best){ best = l[c]; bi = c; }
      }
      mask |= 1u<<bi;
    }
    float m = -3e38f;
    #pragma unroll
    for (int c=0;c<CCC;++c) m = l[c]>m ? l[c] : m;
    float s = 0.f;
    #pragma unroll
    for (int c=0;c<CCC;++c) s += expf(l[c]-m);
    float inv = 1.0f/s;
    unsigned m2 = mask;
    for (int j=0;j<KTOP;++j){
      int ci = __ffs(m2)-1; m2 &= m2-1u;
      unsigned rest = mask & ~(1u<<ci);
      int v[3]; unsigned r2 = rest;
      #pragma unroll
      for (int q=0;q<3;++q){ int col = __ffs(r2)-1; r2 &= r2-1u; v[q] = col - (col>ci ? 1:0); }
      int rank = C3i(v[2]) + C2i(v[1]) + v[0];
      int e4 = n*KTOP + j;
      cols[e4] = ci; ranks[e4] = rank; fiSel[e4] = expf(l[ci]-m)*inv;
    }
  }
}

// ===== stage B2: nodeCnt/nodeList via LDS batching (R3-proven, 192 device atomics) =====
__global__ __launch_bounds__(256) void k_nlist(const int* __restrict__ cols,
    int* __restrict__ nodeCnt, int* __restrict__ nodeList){
  __shared__ int lcnt[CCC];
  __shared__ int lbase[CCC];
  int t = threadIdx.x;
  if (t < CCC) lcnt[t] = 0;
  __syncthreads();
  int n = blockIdx.x*256 + t;
  int mycis[KTOP], mypos[KTOP];
  #pragma unroll
  for (int j=0;j<KTOP;++j){
    int ci = cols[n*KTOP+j];
    mycis[j] = ci;
    mypos[j] = atomicAdd(&lcnt[ci], 1);
  }
  __syncthreads();
  if (t < CCC) lbase[t] = atomicAdd(&nodeCnt[t*16], lcnt[t]);
  __syncthreads();
  #pragma unroll
  for (int j=0;j<KTOP;++j){
    int ci = mycis[j];
    nodeList[ci*NN + lbase[ci] + mypos[j]] = n*KTOP + j;
  }
}

// ===== stage C: class feature sums (R1-proven high-TLP atomics, 6144 blocks) =====
__global__ __launch_bounds__(256) void k_accF(const float* __restrict__ X,
    const int* __restrict__ cols, const int* __restrict__ ranks,
    const float* __restrict__ fiSel, float* __restrict__ F, float* __restrict__ cnt){
  int e = blockIdx.x*2 + (threadIdx.x>>7);
  int h = threadIdx.x & 127;
  int ci = cols[e], rank = ranks[e];
  float fi = fiSel[e];
  int n = e >> 2;
  float v = X[(n*CCC+ci)*HH + h] * fi;
  atomicAdd(&F[(ci*NCLS+rank)*HH + h], v);
  if (h==0) atomicAdd(&cnt[ci*NCLS+rank], 1.0f);
}

// ====== stage D: pairs + singles + degrees + inclusion-exclusion agg (R1-proven) ======
__global__ __launch_bounds__(256) void k_graph(const float* __restrict__ F,
    const float* __restrict__ cnt, float* __restrict__ agg){
  int cb = blockIdx.x, ci = blockIdx.y, t = threadIdx.x;
  __shared__ float cntl[NCLS];
  __shared__ float PcS[105], UcS[15];
  __shared__ int   abcs[NCLS];   // a | b<<5 | c<<10
  __shared__ int   prs[NCLS];    // pab | pac<<10 | pbc<<20
  __shared__ float Fl[NCLS*GCP];
  __shared__ float P[105*GCP];
  __shared__ float U[15*GCP];
  const float* Fc = F + (size_t)ci*NCLS*HH + cb*GCP;

  for (int i=t; i<NCLS*2; i+=256){
    int r = i>>1, hf = i&1;
    float4 v = *(const float4*)(Fc + (size_t)r*HH + hf*4);
    *(float4*)(&Fl[r*GCP + hf*4]) = v;
  }
  for (int r=t; r<NCLS; r+=256){
    cntl[r] = cnt[ci*NCLS+r];
    int c=2; while (c<14 && C3i(c+1)<=r) c++;
    int rem = r - C3i(c);
    int b=1; while (b<c-1 && C2i(b+1)<=rem) b++;
    int a = rem - C2i(b);
    abcs[r] = a | (b<<5) | (c<<10);
    prs[r] = (C2i(b)+a) | ((C2i(c)+a)<<10) | ((C2i(c)+b)<<20);
  }
  __syncthreads();
  if (t<105){
    int pb=1; while (pb<14 && C2i(pb+1)<=t) pb++;
    int pa = t - C2i(pb);
    float s=0.f;
    #pragma unroll
    for (int z=0;z<15;++z){
      if (z==pa||z==pb) continue;
      int lo,mid,hi;
      if (z<pa){lo=z;mid=pa;hi=pb;} else if (z<pb){lo=pa;mid=z;hi=pb;} else {lo=pa;mid=pb;hi=z;}
      s += cntl[C3i(hi)+C2i(mid)+lo];
    }
    PcS[t]=s;
  }
  __syncthreads();
  if (t<15){
    float s=0.f;
    #pragma unroll
    for (int y=0;y<15;++y){
      if (y==t) continue;
      int lo = t<y?t:y, hi = t<y?y:t;
      s += PcS[C2i(hi)+lo];
    }
    UcS[t]=0.5f*s;
  }
  __syncthreads();
  for (int idx=t; idx<105*GCP; idx+=256){
    int p = idx/GCP, col = idx&(GCP-1);
    int pb=1; while (pb<14 && C2i(pb+1)<=p) pb++;
    int pa = p - C2i(pb);
    float s=0.f;
    #pragma unroll
    for (int z=0;z<15;++z){
      if (z==pa||z==pb) continue;
      int lo,mid,hi;
      if (z<pa){lo=z;mid=pa;hi=pb;} else if (z<pb){lo=pa;mid=z;hi=pb;} else {lo=pa;mid=pb;hi=z;}
      s += Fl[(C3i(hi)+C2i(mid)+lo)*GCP + col];
    }
    P[idx]=s;
  }
  __syncthreads();
  for (int idx=t; idx<15*GCP; idx+=256){
    int x = idx/GCP, col = idx&(GCP-1);
    float s=0.f;
    #pragma unroll
    for (int y=0;y<15;++y){
      if (y==x) continue;
      int lo = x<y?x:y, hi = x<y?y:x;
      s += P[(C2i(hi)+lo)*GCP + col];
    }
    U[idx]=0.5f*s;
  }
  __syncthreads();
  for (int idx=t; idx<NCLS*GCP; idx+=256){
    int r = idx/GCP, col = idx&(GCP-1);
    int v1=abcs[r]; int a=v1&31,b=(v1>>5)&31,c=(v1>>10)&31;
    int v2=prs[r];  int pab=v2&1023,pac=(v2>>10)&1023,pbc=(v2>>20)&1023;
    float deg = UcS[a]+UcS[b]+UcS[c]-PcS[pab]-PcS[pac]-PcS[pbc]+cntl[r];
    float invd = 1.0f/fmaxf(deg,1.0f);
    float v = U[a*GCP+col]+U[b*GCP+col]+U[c*GCP+col]
            - P[pab*GCP+col]-P[pac*GCP+col]-P[pbc*GCP+col]
            + Fl[r*GCP+col];
    agg[(size_t)ci*NCLS*HH + (size_t)r*HH + cb*GCP + col] = v*invd;
  }
}

// ========== stage E1: AggWl = Agg @ Wl^T + bl (per class, in-place, f16 MFMA) ==========
__global__ __launch_bounds__(256) void k_aggwl(float* __restrict__ agg,
    const _Float16* __restrict__ Wlh, const float* __restrict__ bl){
  int t = threadIdx.x;
  int w = t >> 6;
  int lane = t & 63;
  int l15 = lane & 15, quad = lane >> 4;
  int ci = blockIdx.y;
  int base = blockIdx.x * MT;
  int rowA = base + 16*w + l15; if (rowA > NCLS-1) rowA = NCLS-1;

  const float* arow = agg + ((size_t)ci*NCLS + rowA)*HH;
  h8 af[4];
  #pragma unroll
  for (int c=0;c<4;++c){
    float4 u = *(const float4*)(arow + c*32 + quad*8);
    float4 v = *(const float4*)(arow + c*32 + quad*8 + 4);
    float xv[8] = {u.x,u.y,u.z,u.w,v.x,v.y,v.z,v.w};
    #pragma unroll
    for (int j=0;j<8;++j) af[c][j] = (_Float16)xv[j];
  }

  f4 acc[8];
  #pragma unroll
  for (int nt=0;nt<8;++nt) acc[nt] = (f4){0.f,0.f,0.f,0.f};

  const _Float16* Wc = Wlh + (size_t)ci*HH*HH;
  #pragma unroll
  for (int c=0;c<4;++c){
    #pragma unroll
    for (int nt=0;nt<8;++nt){
      int o = nt*16 + l15;
      h8 bh = *(const h8*)(Wc + (size_t)o*HH + c*32 + quad*8);
      acc[nt] = __builtin_amdgcn_mfma_f32_16x16x32_f16(af[c], bh, acc[nt], 0,0,0);
    }
  }
  #pragma unroll
  for (int r=0;r<4;++r){
    int row2 = base + 16*w + quad*4 + r;
    if (row2 < NCLS){
      float* drow = agg + ((size_t)ci*NCLS + row2)*HH;
      #pragma unroll
      for (int nt=0;nt<8;++nt){
        int o = nt*16 + l15;
        drow[o] = acc[nt][r] + bl[ci*HH + o];
      }
    }
  }
}

// ========== stage E2: hc = relu(AggWl[class] + fi*X @ Wr^T) (f16 MFMA) ==========
__global__ __launch_bounds__(256) void k_hc2(const float* __restrict__ X,
    const _Float16* __restrict__ Wrh,
    const int* __restrict__ ranks, const float* __restrict__ fiSel,
    const int* __restrict__ nodeCnt, const int* __restrict__ nodeList,
    const float* __restrict__ aggwl, float* __restrict__ hcBuf, float* __restrict__ sums){
  int ci = blockIdx.y;
  int cntc = nodeCnt[ci*16];
  int base = blockIdx.x * MT;
  if (base >= cntc) return;
  __shared__ float rb[8];
  int t = threadIdx.x;
  int w = t >> 6;
  int lane = t & 63;
  int l15 = lane & 15, quad = lane >> 4;

  int pA = base + 16*w + l15;
  float fi = 0.f; int nA = 0;
  if (pA < cntc){
    int e = nodeList[ci*NN + pA];
    fi = fiSel[e]; nA = e >> 2;
  }
  const float* xrow = X + ((size_t)nA*CCC + ci)*HH;
  h8 af[4];
  #pragma unroll
  for (int c=0;c<4;++c){
    float4 u = *(const float4*)(xrow + c*32 + quad*8);
    float4 v = *(const float4*)(xrow + c*32 + quad*8 + 4);
    float xv[8] = {u.x,u.y,u.z,u.w,v.x,v.y,v.z,v.w};
    #pragma unroll
    for (int j=0;j<8;++j) af[c][j] = (_Float16)(xv[j]*fi);
  }

  f4 acc[8];
  #pragma unroll
  for (int nt=0;nt<8;++nt) acc[nt] = (f4){0.f,0.f,0.f,0.f};

  const _Float16* Wc = Wrh + (size_t)ci*HH*HH;
  #pragma unroll
  for (int c=0;c<4;++c){
    #pragma unroll
    for (int nt=0;nt<8;++nt){
      int o = nt*16 + l15;
      h8 bh = *(const h8*)(Wc + (size_t)o*HH + c*32 + quad*8);
      acc[nt] = __builtin_amdgcn_mfma_f32_16x16x32_f16(af[c], bh, acc[nt], 0,0,0);
    }
  }

  float s1 = 0.f, s2 = 0.f;
  #pragma unroll
  for (int r=0;r<4;++r){
    int pD = base + 16*w + quad*4 + r;
    int e2 = -1, rk2 = 0;
    if (pD < cntc){ e2 = nodeList[ci*NN + pD]; rk2 = ranks[e2]; }
    if (e2 >= 0){
      const float* G = aggwl + ((size_t)ci*NCLS + rk2)*HH;
      float* drow = hcBuf + (size_t)e2*HH;
      #pragma unroll
      for (int nt=0;nt<8;++nt){
        int o = nt*16 + l15;
        float vv = acc[nt][r] + G[o];
        vv = vv>0.f ? vv : 0.f;
        drow[o] = vv;
        s1 += vv; s2 += vv*vv;
      }
    }
  }
  #pragma unroll
  for (int m=1;m<64;m<<=1){ s1 += __shfl_xor(s1,m); s2 += __shfl_xor(s2,m); }
  if (lane == 0){ rb[w] = s1; rb[4+w] = s2; }
  __syncthreads();
  if (t==0){
    atomicAdd(&sums[ci],    rb[0]+rb[1]+rb[2]+rb[3]);
    atomicAdd(&sums[16+ci], rb[4]+rb[5]+rb[6]+rb[7]);
  }
}

// ========== stage F: masked mean/var normalize, write output ==========
__global__ __launch_bounds__(256) void k_out(const float* __restrict__ hcBuf,
    const int* __restrict__ cols, const int* __restrict__ nodeCnt,
    const float* __restrict__ sums, float* __restrict__ out){
  int idx = blockIdx.x*256 + threadIdx.x;
  int e = idx >> 7;
  int ci = cols[e];
  float cntf = (float)nodeCnt[ci*16];
  float nel = fmaxf(cntf * (float)HH, 1.0f);
  float mu = sums[ci]/nel;
  float var = sums[16+ci]/nel - mu*mu;
  out[idx] = (hcBuf[idx]-mu)/sqrtf(var+EPSF);
}

extern "C" void kernel_launch(void* const* d_in, const int* in_sizes, int n_in,
                              void* d_out, int out_size, void* d_ws, size_t ws_size,
                              hipStream_t stream){
  const float* X    = (const float*)d_in[0];
  const float* W1   = (const float*)d_in[1];
  const float* b1   = (const float*)d_in[2];
  const float* ln_g = (const float*)d_in[3];
  const float* ln_b = (const float*)d_in[4];
  const float* W2   = (const float*)d_in[5];
  const float* b2   = (const float*)d_in[6];
  const float* Wl   = (const float*)d_in[7];
  const float* bl   = (const float*)d_in[8];
  const float* Wr   = (const float*)d_in[9];
  float* ws = (float*)d_ws;
  float* F      = ws + OFF_F;
  float* cnt    = ws + OFF_CNT;
  float* sums   = ws + OFF_SUMS;
  int*   nodeCnt= (int*)(ws + OFF_NCNT);
  int*   cols   = (int*)(ws + OFF_COLS);
  int*   ranks  = (int*)(ws + OFF_RANKS);
  float* fiSel  = ws + OFF_FISEL;
  int*   nodeList=(int*)(ws + OFF_NLIST);
  float* agg    = ws + OFF_AGG;
  float* hcBuf  = ws + OFF_HC;
  _Float16* hbase = (_Float16*)(ws + OFF_HALF);
  float* out    = (float*)d_out;

  k_cvt    <<<dim3(64), dim3(256), 0, stream>>>(W1, hbase, ws);
  k_fused  <<<dim3(NN*CCC/MT), dim3(256), 0, stream>>>(X, hbase+HOFF_W1H, hbase+HOFF_W1L,
                                                       b1, ln_g, ln_b, W2, b2, Wl, Wr,
                                                       hbase, F, cols, ranks, fiSel);
  k_nlist  <<<dim3(NN/256), dim3(256), 0, stream>>>(cols, nodeCnt, nodeList);
  k_accF   <<<dim3(NN*KTOP/2), dim3(256), 0, stream>>>(X, cols, ranks, fiSel, F, cnt);
  k_graph  <<<dim3(GCB,16), dim3(256), 0, stream>>>(F, cnt, agg);
  k_aggwl  <<<dim3((NCLS+MT-1)/MT,16), dim3(256), 0, stream>>>(agg, hbase+HOFF_WLH, bl);
  k_hc2    <<<dim3((NN/MT),16), dim3(256), 0, stream>>>(X, hbase+HOFF_WRH, ranks, fiSel,
                                                        nodeCnt, nodeList, agg, hcBuf, sums);
  k_out    <<<dim3(NN*KTOP*HH/256), dim3(256), 0, stream>>>(hcBuf, cols, nodeCnt, sums, out);
}

// Round 10
// 165.544 us; speedup vs baseline: 3.5432x; 1.0601x over previous
//
#include <hip/hip_runtime.h>

#define NN 3072
#define CCC 16
#define HH 128
#define KTOP 4
#define NCLS 455   // C(15,3)
#define EPSF 1e-5f

// ---------------- ws layout (float offsets) ----------------
#define OFF_F       0
#define SZ_F        (16*NCLS*HH)            // 931840
#define OFF_CNT     (OFF_F + SZ_F)
#define SZ_CNT      (16*NCLS)
#define OFF_SUMS    (OFF_CNT + SZ_CNT)
#define SZ_SUMS     32
#define OFF_NCNT    (OFF_SUMS + SZ_SUMS)    // int nodeCnt[16*16]
#define SZ_NCNT     256
#define SMALL_ZERO  (SZ_CNT + SZ_SUMS + SZ_NCNT)  // cnt+sums+nodeCnt (zeroed by k_fused blk0)
#define OFF_COLS    (OFF_NCNT + SZ_NCNT)
#define SZ_E        (NN*KTOP)
#define OFF_RANKS   (OFF_COLS + SZ_E)
#define OFF_FISEL   (OFF_RANKS + SZ_E)
#define OFF_NLIST   (OFF_FISEL + SZ_E)
#define SZ_NLIST    (16*NN)
#define OFF_AGG     (OFF_NLIST + SZ_NLIST)
#define OFF_HC      (OFF_AGG + SZ_F)
#define SZ_HC       (NN*KTOP*HH)
#define OFF_HALF    (OFF_HC + SZ_HC)
#define HOFF_WLH    0
#define HOFF_WRH    262144

#define MT 64
#define GCP 8              // k_graph cols per block
#define GCB (HH/GCP)
#define W1P 132            // padded row stride (f16) for W1 LDS: 2-way bank aliasing only

typedef _Float16 h8 __attribute__((ext_vector_type(8)));
typedef float    f4 __attribute__((ext_vector_type(4)));

__device__ __forceinline__ int C2i(int x){ return x*(x-1)/2; }
__device__ __forceinline__ int C3i(int x){ return x*(x-1)*(x-2)/6; }

// ===== stage A+B fused (6-dispatch pipeline): W1->LDS hi/lo cvt, logits MFMA,
// ===== in-LDS topk/softmax. Folded: F zeroing, Wl/Wr f16 cvt, small-zero (blk 0).
__global__ __launch_bounds__(256) void k_fused(const float* __restrict__ X,
    const float* __restrict__ W1,
    const float* __restrict__ b1, const float* __restrict__ ln_g,
    const float* __restrict__ ln_b, const float* __restrict__ W2,
    const float* __restrict__ b2,
    const float* __restrict__ Wl, const float* __restrict__ Wr,
    _Float16* __restrict__ hbase, float* __restrict__ F, float* __restrict__ ws,
    int* __restrict__ cols, int* __restrict__ ranks, float* __restrict__ fiSel){
  __shared__ _Float16 w1h_s[HH*W1P];
  __shared__ _Float16 w1l_s[HH*W1P];
  __shared__ float llog[64];
  int t = threadIdx.x;
  int w = t >> 6;
  int lane = t & 63;
  int l15 = lane & 15, quad = lane >> 4;
  int base = blockIdx.x * MT;
  int mA = base + 16*w + l15;

  // ---- W1 -> LDS f16 hi/lo (replaces the k_cvt dispatch; same values) ----
  for (int j = t; j < HH*HH; j += 256){
    int r = j >> 7, c0 = j & 127;
    float x = W1[j];
    _Float16 h = (_Float16)x;
    w1h_s[r*W1P + c0] = h;
    w1l_s[r*W1P + c0] = (_Float16)(x - (float)h);
  }

  // ---- folded housekeeping: zero F + cvt Wl/Wr + (blk 0) small zeros ----
  {
    f4 z4 = (f4){0.f,0.f,0.f,0.f};
    for (int i = blockIdx.x*256 + t; i < SZ_F/4; i += 768*256)
      *(f4*)(F + (size_t)i*4) = z4;
    for (int i = blockIdx.x*256 + t; i < 2*262144; i += 768*256){
      if (i < 262144) hbase[HOFF_WLH + i] = (_Float16)Wl[i];
      else            hbase[HOFF_WRH + (i-262144)] = (_Float16)Wr[i-262144];
    }
    if (blockIdx.x == 0)
      for (int i = t; i < SMALL_ZERO; i += 256) ws[OFF_CNT + i] = 0.f;
  }

  // ---- phase 1: z=relu(X@W1^T+b1); LN; logit=zn.W2+b2 (identical math) ----
  const float* xrow = X + (size_t)mA*HH;
  h8 ah[4], al[4];
  #pragma unroll
  for (int c=0;c<4;++c){
    float4 u = *(const float4*)(xrow + c*32 + quad*8);
    float4 v = *(const float4*)(xrow + c*32 + quad*8 + 4);
    float xv[8] = {u.x,u.y,u.z,u.w,v.x,v.y,v.z,v.w};
    #pragma unroll
    for (int j=0;j<8;++j){
      _Float16 hi = (_Float16)xv[j];
      ah[c][j] = hi;
      al[c][j] = (_Float16)(xv[j] - (float)hi);
    }
  }
  __syncthreads();   // W1 LDS ready

  f4 acc[8];
  #pragma unroll
  for (int nt=0;nt<8;++nt) acc[nt] = (f4){0.f,0.f,0.f,0.f};

  #pragma unroll
  for (int c=0;c<4;++c){
    #pragma unroll
    for (int nt=0;nt<8;++nt){
      int o = nt*16 + l15;
      h8 bh  = *(const h8*)(w1h_s + o*W1P + c*32 + quad*8);
      h8 bl_ = *(const h8*)(w1l_s + o*W1P + c*32 + quad*8);
      acc[nt] = __builtin_amdgcn_mfma_f32_16x16x32_f16(ah[c], bh,  acc[nt], 0,0,0);
      acc[nt] = __builtin_amdgcn_mfma_f32_16x16x32_f16(al[c], bh,  acc[nt], 0,0,0);
      acc[nt] = __builtin_amdgcn_mfma_f32_16x16x32_f16(ah[c], bl_, acc[nt], 0,0,0);
      acc[nt] = __builtin_amdgcn_mfma_f32_16x16x32_f16(al[c], bl_, acc[nt], 0,0,0);
    }
  }

  float bv[8], gv[8], lv[8], wv[8];
  #pragma unroll
  for (int nt=0;nt<8;++nt){
    int o = nt*16 + l15;
    bv[nt]=b1[o]; gv[nt]=ln_g[o]; lv[nt]=ln_b[o]; wv[nt]=W2[o];
  }
  float b2v = b2[0];
  #pragma unroll
  for (int r=0;r<4;++r){
    float z[8];
    float s1=0.f, s2=0.f;
    #pragma unroll
    for (int nt=0;nt<8;++nt){
      float zz = acc[nt][r] + bv[nt];
      zz = zz>0.f ? zz : 0.f;
      z[nt] = zz; s1 += zz; s2 += zz*zz;
    }
    #pragma unroll
    for (int m=1;m<16;m<<=1){ s1 += __shfl_xor(s1,m); s2 += __shfl_xor(s2,m); }
    float mu = s1/(float)HH;
    float var = s2/(float)HH - mu*mu;
    float rs = 1.0f/sqrtf(var+EPSF);
    float s3 = 0.f;
    #pragma unroll
    for (int nt=0;nt<8;++nt){
      float zn = (z[nt]-mu)*rs*gv[nt] + lv[nt];
      s3 += zn*wv[nt];
    }
    #pragma unroll
    for (int m=1;m<16;m<<=1) s3 += __shfl_xor(s3,m);
    if (l15 == 0) llog[16*w + quad*4 + r] = s3 + b2v;
  }
  __syncthreads();

  // ---- phase 2: topk/softmax per node (threads 0..3), plain stores only ----
  if (t < 4){
    int n = blockIdx.x*4 + t;
    float l[CCC];
    #pragma unroll
    for (int c=0;c<CCC;++c) l[c] = llog[t*16+c];
    unsigned mask = 0;
    #pragma unroll
    for (int k=0;k<KTOP;++k){
      float best = -3e38f; int bi = 0;
      #pragma unroll
      for (int c=0;c<CCC;++c){
        bool taken = (mask>>c)&1u;
        if (!taken && l[c] > best){ best = l[c]; bi = c; }
      }
      mask |= 1u<<bi;
    }
    float m = -3e38f;
    #pragma unroll
    for (int c=0;c<CCC;++c) m = l[c]>m ? l[c] : m;
    float s = 0.f;
    #pragma unroll
    for (int c=0;c<CCC;++c) s += expf(l[c]-m);
    float inv = 1.0f/s;
    unsigned m2 = mask;
    for (int j=0;j<KTOP;++j){
      int ci = __ffs(m2)-1; m2 &= m2-1u;
      unsigned rest = mask & ~(1u<<ci);
      int v[3]; unsigned r2 = rest;
      #pragma unroll
      for (int q=0;q<3;++q){ int col = __ffs(r2)-1; r2 &= r2-1u; v[q] = col - (col>ci ? 1:0); }
      int rank = C3i(v[2]) + C2i(v[1]) + v[0];
      int e4 = n*KTOP + j;
      cols[e4] = ci; ranks[e4] = rank; fiSel[e4] = expf(l[ci]-m)*inv;
    }
  }
}

// ===== stage C: class feature sums (high-TLP atomics, 6144 blocks) + nodeList
// ===== build in 12 extra blocks (merged k_nlist, same LDS-batched logic) =====
__global__ __launch_bounds__(256) void k_accF(const float* __restrict__ X,
    const int* __restrict__ cols, const int* __restrict__ ranks,
    const float* __restrict__ fiSel, float* __restrict__ F, float* __restrict__ cnt,
    int* __restrict__ nodeCnt, int* __restrict__ nodeList){
  __shared__ int lcnt[CCC];
  __shared__ int lbase[CCC];
  int t = threadIdx.x;
  if (blockIdx.x < NN*KTOP/2){
    int e = blockIdx.x*2 + (t>>7);
    int h = t & 127;
    int ci = cols[e], rank = ranks[e];
    float fi = fiSel[e];
    int n = e >> 2;
    float v = X[(n*CCC+ci)*HH + h] * fi;
    atomicAdd(&F[(ci*NCLS+rank)*HH + h], v);
    if (h==0) atomicAdd(&cnt[ci*NCLS+rank], 1.0f);
  } else {
    int nb = blockIdx.x - NN*KTOP/2;   // 0..11
    if (t < CCC) lcnt[t] = 0;
    __syncthreads();
    int n = nb*256 + t;
    int mycis[KTOP], mypos[KTOP];
    #pragma unroll
    for (int j=0;j<KTOP;++j){
      int ci = cols[n*KTOP+j];
      mycis[j] = ci;
      mypos[j] = atomicAdd(&lcnt[ci], 1);
    }
    __syncthreads();
    if (t < CCC) lbase[t] = atomicAdd(&nodeCnt[t*16], lcnt[t]);
    __syncthreads();
    #pragma unroll
    for (int j=0;j<KTOP;++j){
      int ci = mycis[j];
      nodeList[ci*NN + lbase[ci] + mypos[j]] = n*KTOP + j;
    }
  }
}

// ====== stage D: pairs + singles + degrees + inclusion-exclusion agg (R1-proven) ======
__global__ __launch_bounds__(256) void k_graph(const float* __restrict__ F,
    const float* __restrict__ cnt, float* __restrict__ agg){
  int cb = blockIdx.x, ci = blockIdx.y, t = threadIdx.x;
  __shared__ float cntl[NCLS];
  __shared__ float PcS[105], UcS[15];
  __shared__ int   abcs[NCLS];   // a | b<<5 | c<<10
  __shared__ int   prs[NCLS];    // pab | pac<<10 | pbc<<20
  __shared__ float Fl[NCLS*GCP];
  __shared__ float P[105*GCP];
  __shared__ float U[15*GCP];
  const float* Fc = F + (size_t)ci*NCLS*HH + cb*GCP;

  for (int i=t; i<NCLS*2; i+=256){
    int r = i>>1, hf = i&1;
    float4 v = *(const float4*)(Fc + (size_t)r*HH + hf*4);
    *(float4*)(&Fl[r*GCP + hf*4]) = v;
  }
  for (int r=t; r<NCLS; r+=256){
    cntl[r] = cnt[ci*NCLS+r];
    int c=2; while (c<14 && C3i(c+1)<=r) c++;
    int rem = r - C3i(c);
    int b=1; while (b<c-1 && C2i(b+1)<=rem) b++;
    int a = rem - C2i(b);
    abcs[r] = a | (b<<5) | (c<<10);
    prs[r] = (C2i(b)+a) | ((C2i(c)+a)<<10) | ((C2i(c)+b)<<20);
  }
  __syncthreads();
  if (t<105){
    int pb=1; while (pb<14 && C2i(pb+1)<=t) pb++;
    int pa = t - C2i(pb);
    float s=0.f;
    #pragma unroll
    for (int z=0;z<15;++z){
      if (z==pa||z==pb) continue;
      int lo,mid,hi;
      if (z<pa){lo=z;mid=pa;hi=pb;} else if (z<pb){lo=pa;mid=z;hi=pb;} else {lo=pa;mid=pb;hi=z;}
      s += cntl[C3i(hi)+C2i(mid)+lo];
    }
    PcS[t]=s;
  }
  __syncthreads();
  if (t<15){
    float s=0.f;
    #pragma unroll
    for (int y=0;y<15;++y){
      if (y==t) continue;
      int lo = t<y?t:y, hi = t<y?y:t;
      s += PcS[C2i(hi)+lo];
    }
    UcS[t]=0.5f*s;
  }
  __syncthreads();
  for (int idx=t; idx<105*GCP; idx+=256){
    int p = idx/GCP, col = idx&(GCP-1);
    int pb=1; while (pb<14 && C2i(pb+1)<=p) pb++;
    int pa = p - C2i(pb);
    float s=0.f;
    #pragma unroll
    for (int z=0;z<15;++z){
      if (z==pa||z==pb) continue;
      int lo,mid,hi;
      if (z<pa){lo=z;mid=pa;hi=pb;} else if (z<pb){lo=pa;mid=z;hi=pb;} else {lo=pa;mid=pb;hi=z;}
      s += Fl[(C3i(hi)+C2i(mid)+lo)*GCP + col];
    }
    P[idx]=s;
  }
  __syncthreads();
  for (int idx=t; idx<15*GCP; idx+=256){
    int x = idx/GCP, col = idx&(GCP-1);
    float s=0.f;
    #pragma unroll
    for (int y=0;y<15;++y){
      if (y==x) continue;
      int lo = x<y?x:y, hi = x<y?y:x;
      s += P[(C2i(hi)+lo)*GCP + col];
    }
    U[idx]=0.5f*s;
  }
  __syncthreads();
  for (int idx=t; idx<NCLS*GCP; idx+=256){
    int r = idx/GCP, col = idx&(GCP-1);
    int v1=abcs[r]; int a=v1&31,b=(v1>>5)&31,c=(v1>>10)&31;
    int v2=prs[r];  int pab=v2&1023,pac=(v2>>10)&1023,pbc=(v2>>20)&1023;
    float deg = UcS[a]+UcS[b]+UcS[c]-PcS[pab]-PcS[pac]-PcS[pbc]+cntl[r];
    float invd = 1.0f/fmaxf(deg,1.0f);
    float v = U[a*GCP+col]+U[b*GCP+col]+U[c*GCP+col]
            - P[pab*GCP+col]-P[pac*GCP+col]-P[pbc*GCP+col]
            + Fl[r*GCP+col];
    agg[(size_t)ci*NCLS*HH + (size_t)r*HH + cb*GCP + col] = v*invd;
  }
}

// ========== stage E1: AggWl = Agg @ Wl^T + bl (per class, in-place, f16 MFMA) ==========
__global__ __launch_bounds__(256) void k_aggwl(float* __restrict__ agg,
    const _Float16* __restrict__ Wlh, const float* __restrict__ bl){
  int t = threadIdx.x;
  int w = t >> 6;
  int lane = t & 63;
  int l15 = lane & 15, quad = lane >> 4;
  int ci = blockIdx.y;
  int base = blockIdx.x * MT;
  int rowA = base + 16*w + l15; if (rowA > NCLS-1) rowA = NCLS-1;

  const float* arow = agg + ((size_t)ci*NCLS + rowA)*HH;
  h8 af[4];
  #pragma unroll
  for (int c=0;c<4;++c){
    float4 u = *(const float4*)(arow + c*32 + quad*8);
    float4 v = *(const float4*)(arow + c*32 + quad*8 + 4);
    float xv[8] = {u.x,u.y,u.z,u.w,v.x,v.y,v.z,v.w};
    #pragma unroll
    for (int j=0;j<8;++j) af[c][j] = (_Float16)xv[j];
  }

  f4 acc[8];
  #pragma unroll
  for (int nt=0;nt<8;++nt) acc[nt] = (f4){0.f,0.f,0.f,0.f};

  const _Float16* Wc = Wlh + (size_t)ci*HH*HH;
  #pragma unroll
  for (int c=0;c<4;++c){
    #pragma unroll
    for (int nt=0;nt<8;++nt){
      int o = nt*16 + l15;
      h8 bh = *(const h8*)(Wc + (size_t)o*HH + c*32 + quad*8);
      acc[nt] = __builtin_amdgcn_mfma_f32_16x16x32_f16(af[c], bh, acc[nt], 0,0,0);
    }
  }
  #pragma unroll
  for (int r=0;r<4;++r){
    int row2 = base + 16*w + quad*4 + r;
    if (row2 < NCLS){
      float* drow = agg + ((size_t)ci*NCLS + row2)*HH;
      #pragma unroll
      for (int nt=0;nt<8;++nt){
        int o = nt*16 + l15;
        drow[o] = acc[nt][r] + bl[ci*HH + o];
      }
    }
  }
}

// ========== stage E2: hc = relu(AggWl[class] + fi*X @ Wr^T) (f16 MFMA) ==========
__global__ __launch_bounds__(256) void k_hc2(const float* __restrict__ X,
    const _Float16* __restrict__ Wrh,
    const int* __restrict__ ranks, const float* __restrict__ fiSel,
    const int* __restrict__ nodeCnt, const int* __restrict__ nodeList,
    const float* __restrict__ aggwl, float* __restrict__ hcBuf, float* __restrict__ sums){
  int ci = blockIdx.y;
  int cntc = nodeCnt[ci*16];
  int base = blockIdx.x * MT;
  if (base >= cntc) return;
  __shared__ float rb[8];
  int t = threadIdx.x;
  int w = t >> 6;
  int lane = t & 63;
  int l15 = lane & 15, quad = lane >> 4;

  int pA = base + 16*w + l15;
  float fi = 0.f; int nA = 0;
  if (pA < cntc){
    int e = nodeList[ci*NN + pA];
    fi = fiSel[e]; nA = e >> 2;
  }
  const float* xrow = X + ((size_t)nA*CCC + ci)*HH;
  h8 af[4];
  #pragma unroll
  for (int c=0;c<4;++c){
    float4 u = *(const float4*)(xrow + c*32 + quad*8);
    float4 v = *(const float4*)(xrow + c*32 + quad*8 + 4);
    float xv[8] = {u.x,u.y,u.z,u.w,v.x,v.y,v.z,v.w};
    #pragma unroll
    for (int j=0;j<8;++j) af[c][j] = (_Float16)(xv[j]*fi);
  }

  f4 acc[8];
  #pragma unroll
  for (int nt=0;nt<8;++nt) acc[nt] = (f4){0.f,0.f,0.f,0.f};

  const _Float16* Wc = Wrh + (size_t)ci*HH*HH;
  #pragma unroll
  for (int c=0;c<4;++c){
    #pragma unroll
    for (int nt=0;nt<8;++nt){
      int o = nt*16 + l15;
      h8 bh = *(const h8*)(Wc + (size_t)o*HH + c*32 + quad*8);
      acc[nt] = __builtin_amdgcn_mfma_f32_16x16x32_f16(af[c], bh, acc[nt], 0,0,0);
    }
  }

  float s1 = 0.f, s2 = 0.f;
  #pragma unroll
  for (int r=0;r<4;++r){
    int pD = base + 16*w + quad*4 + r;
    int e2 = -1, rk2 = 0;
    if (pD < cntc){ e2 = nodeList[ci*NN + pD]; rk2 = ranks[e2]; }
    if (e2 >= 0){
      const float* G = aggwl + ((size_t)ci*NCLS + rk2)*HH;
      float* drow = hcBuf + (size_t)e2*HH;
      #pragma unroll
      for (int nt=0;nt<8;++nt){
        int o = nt*16 + l15;
        float vv = acc[nt][r] + G[o];
        vv = vv>0.f ? vv : 0.f;
        drow[o] = vv;
        s1 += vv; s2 += vv*vv;
      }
    }
  }
  #pragma unroll
  for (int m=1;m<64;m<<=1){ s1 += __shfl_xor(s1,m); s2 += __shfl_xor(s2,m); }
  if (lane == 0){ rb[w] = s1; rb[4+w] = s2; }
  __syncthreads();
  if (t==0){
    atomicAdd(&sums[ci],    rb[0]+rb[1]+rb[2]+rb[3]);
    atomicAdd(&sums[16+ci], rb[4]+rb[5]+rb[6]+rb[7]);
  }
}

// ========== stage F: masked mean/var normalize, write output ==========
__global__ __launch_bounds__(256) void k_out(const float* __restrict__ hcBuf,
    const int* __restrict__ cols, const int* __restrict__ nodeCnt,
    const float* __restrict__ sums, float* __restrict__ out){
  int idx = blockIdx.x*256 + threadIdx.x;
  int e = idx >> 7;
  int ci = cols[e];
  float cntf = (float)nodeCnt[ci*16];
  float nel = fmaxf(cntf * (float)HH, 1.0f);
  float mu = sums[ci]/nel;
  float var = sums[16+ci]/nel - mu*mu;
  out[idx] = (hcBuf[idx]-mu)/sqrtf(var+EPSF);
}

extern "C" void kernel_launch(void* const* d_in, const int* in_sizes, int n_in,
                              void* d_out, int out_size, void* d_ws, size_t ws_size,
                              hipStream_t stream){
  const float* X    = (const float*)d_in[0];
  const float* W1   = (const float*)d_in[1];
  const float* b1   = (const float*)d_in[2];
  const float* ln_g = (const float*)d_in[3];
  const float* ln_b = (const float*)d_in[4];
  const float* W2   = (const float*)d_in[5];
  const float* b2   = (const float*)d_in[6];
  const float* Wl   = (const float*)d_in[7];
  const float* bl   = (const float*)d_in[8];
  const float* Wr   = (const float*)d_in[9];
  float* ws = (float*)d_ws;
  float* F      = ws + OFF_F;
  float* cnt    = ws + OFF_CNT;
  float* sums   = ws + OFF_SUMS;
  int*   nodeCnt= (int*)(ws + OFF_NCNT);
  int*   cols   = (int*)(ws + OFF_COLS);
  int*   ranks  = (int*)(ws + OFF_RANKS);
  float* fiSel  = ws + OFF_FISEL;
  int*   nodeList=(int*)(ws + OFF_NLIST);
  float* agg    = ws + OFF_AGG;
  float* hcBuf  = ws + OFF_HC;
  _Float16* hbase = (_Float16*)(ws + OFF_HALF);
  float* out    = (float*)d_out;

  k_fused  <<<dim3(NN*CCC/MT), dim3(256), 0, stream>>>(X, W1, b1, ln_g, ln_b, W2, b2,
                                                       Wl, Wr, hbase, F, ws,
                                                       cols, ranks, fiSel);
  k_accF   <<<dim3(NN*KTOP/2 + 12), dim3(256), 0, stream>>>(X, cols, ranks, fiSel, F, cnt,
                                                            nodeCnt, nodeList);
  k_graph  <<<dim3(GCB,16), dim3(256), 0, stream>>>(F, cnt, agg);
  k_aggwl  <<<dim3((NCLS+MT-1)/MT,16), dim3(256), 0, stream>>>(agg, hbase+HOFF_WLH, bl);
  k_hc2    <<<dim3((NN/MT),16), dim3(256), 0, stream>>>(X, hbase+HOFF_WRH, ranks, fiSel,
                                                        nodeCnt, nodeList, agg, hcBuf, sums);
  k_out    <<<dim3(NN*KTOP*HH/256), dim3(256), 0, stream>>>(hcBuf, cols, nodeCnt, sums, out);
}

// Round 11
// 161.738 us; speedup vs baseline: 3.6266x; 1.0235x over previous
//
#include <hip/hip_runtime.h>

#define NN 3072
#define CCC 16
#define HH 128
#define KTOP 4
#define NCLS 455   // C(15,3)
#define EPSF 1e-5f

// ---------------- ws layout (float offsets) ----------------
#define OFF_F       0
#define SZ_F        (16*NCLS*HH)            // 931840
#define OFF_CNT     (OFF_F + SZ_F)
#define SZ_CNT      (16*NCLS)
#define OFF_SUMS    (OFF_CNT + SZ_CNT)
#define SZ_SUMS     32
#define OFF_NCNT    (OFF_SUMS + SZ_SUMS)    // int nodeCnt[16*16]
#define SZ_NCNT     256
#define SMALL_ZERO  (SZ_CNT + SZ_SUMS + SZ_NCNT)  // cnt+sums+nodeCnt (zeroed by k_fused blk0)
#define OFF_COLS    (OFF_NCNT + SZ_NCNT)
#define SZ_E        (NN*KTOP)
#define OFF_RANKS   (OFF_COLS + SZ_E)
#define OFF_FISEL   (OFF_RANKS + SZ_E)
#define OFF_NLIST   (OFF_FISEL + SZ_E)
#define SZ_NLIST    (16*NN)
#define OFF_AGG     (OFF_NLIST + SZ_NLIST)
#define OFF_HC      (OFF_AGG + SZ_F)
#define SZ_HC       (NN*KTOP*HH)
#define OFF_HALF    (OFF_HC + SZ_HC)
#define HOFF_WLH    0
#define HOFF_WRH    262144

#define MT 64
#define GCP 8              // k_graph cols per block
#define GCB (HH/GCP)
#define W1P 132            // padded row stride (f16) for W1 LDS: 2-way bank aliasing only

typedef _Float16 h8 __attribute__((ext_vector_type(8)));
typedef float    f4 __attribute__((ext_vector_type(4)));

__device__ __forceinline__ int C2i(int x){ return x*(x-1)/2; }
__device__ __forceinline__ int C3i(int x){ return x*(x-1)*(x-2)/6; }

// ===== stage A+B fused: W1->LDS hi/lo cvt, logits MFMA, in-LDS topk/softmax.
// ===== Folded: F zeroing, Wl/Wr f16 cvt, small-zero (blk 0).  (R10-proven)
__global__ __launch_bounds__(256) void k_fused(const float* __restrict__ X,
    const float* __restrict__ W1,
    const float* __restrict__ b1, const float* __restrict__ ln_g,
    const float* __restrict__ ln_b, const float* __restrict__ W2,
    const float* __restrict__ b2,
    const float* __restrict__ Wl, const float* __restrict__ Wr,
    _Float16* __restrict__ hbase, float* __restrict__ F, float* __restrict__ ws,
    int* __restrict__ cols, int* __restrict__ ranks, float* __restrict__ fiSel){
  __shared__ _Float16 w1h_s[HH*W1P];
  __shared__ _Float16 w1l_s[HH*W1P];
  __shared__ float llog[64];
  int t = threadIdx.x;
  int w = t >> 6;
  int lane = t & 63;
  int l15 = lane & 15, quad = lane >> 4;
  int base = blockIdx.x * MT;
  int mA = base + 16*w + l15;

  // ---- W1 -> LDS f16 hi/lo (same values as the old k_cvt) ----
  for (int j = t; j < HH*HH; j += 256){
    int r = j >> 7, c0 = j & 127;
    float x = W1[j];
    _Float16 h = (_Float16)x;
    w1h_s[r*W1P + c0] = h;
    w1l_s[r*W1P + c0] = (_Float16)(x - (float)h);
  }

  // ---- folded housekeeping: zero F + cvt Wl/Wr + (blk 0) small zeros ----
  {
    f4 z4 = (f4){0.f,0.f,0.f,0.f};
    for (int i = blockIdx.x*256 + t; i < SZ_F/4; i += 768*256)
      *(f4*)(F + (size_t)i*4) = z4;
    for (int i = blockIdx.x*256 + t; i < 2*262144; i += 768*256){
      if (i < 262144) hbase[HOFF_WLH + i] = (_Float16)Wl[i];
      else            hbase[HOFF_WRH + (i-262144)] = (_Float16)Wr[i-262144];
    }
    if (blockIdx.x == 0)
      for (int i = t; i < SMALL_ZERO; i += 256) ws[OFF_CNT + i] = 0.f;
  }

  // ---- phase 1: z=relu(X@W1^T+b1); LN; logit=zn.W2+b2 (identical math) ----
  const float* xrow = X + (size_t)mA*HH;
  h8 ah[4], al[4];
  #pragma unroll
  for (int c=0;c<4;++c){
    float4 u = *(const float4*)(xrow + c*32 + quad*8);
    float4 v = *(const float4*)(xrow + c*32 + quad*8 + 4);
    float xv[8] = {u.x,u.y,u.z,u.w,v.x,v.y,v.z,v.w};
    #pragma unroll
    for (int j=0;j<8;++j){
      _Float16 hi = (_Float16)xv[j];
      ah[c][j] = hi;
      al[c][j] = (_Float16)(xv[j] - (float)hi);
    }
  }
  __syncthreads();   // W1 LDS ready

  f4 acc[8];
  #pragma unroll
  for (int nt=0;nt<8;++nt) acc[nt] = (f4){0.f,0.f,0.f,0.f};

  #pragma unroll
  for (int c=0;c<4;++c){
    #pragma unroll
    for (int nt=0;nt<8;++nt){
      int o = nt*16 + l15;
      h8 bh  = *(const h8*)(w1h_s + o*W1P + c*32 + quad*8);
      h8 bl_ = *(const h8*)(w1l_s + o*W1P + c*32 + quad*8);
      acc[nt] = __builtin_amdgcn_mfma_f32_16x16x32_f16(ah[c], bh,  acc[nt], 0,0,0);
      acc[nt] = __builtin_amdgcn_mfma_f32_16x16x32_f16(al[c], bh,  acc[nt], 0,0,0);
      acc[nt] = __builtin_amdgcn_mfma_f32_16x16x32_f16(ah[c], bl_, acc[nt], 0,0,0);
      acc[nt] = __builtin_amdgcn_mfma_f32_16x16x32_f16(al[c], bl_, acc[nt], 0,0,0);
    }
  }

  float bv[8], gv[8], lv[8], wv[8];
  #pragma unroll
  for (int nt=0;nt<8;++nt){
    int o = nt*16 + l15;
    bv[nt]=b1[o]; gv[nt]=ln_g[o]; lv[nt]=ln_b[o]; wv[nt]=W2[o];
  }
  float b2v = b2[0];
  #pragma unroll
  for (int r=0;r<4;++r){
    float z[8];
    float s1=0.f, s2=0.f;
    #pragma unroll
    for (int nt=0;nt<8;++nt){
      float zz = acc[nt][r] + bv[nt];
      zz = zz>0.f ? zz : 0.f;
      z[nt] = zz; s1 += zz; s2 += zz*zz;
    }
    #pragma unroll
    for (int m=1;m<16;m<<=1){ s1 += __shfl_xor(s1,m); s2 += __shfl_xor(s2,m); }
    float mu = s1/(float)HH;
    float var = s2/(float)HH - mu*mu;
    float rs = 1.0f/sqrtf(var+EPSF);
    float s3 = 0.f;
    #pragma unroll
    for (int nt=0;nt<8;++nt){
      float zn = (z[nt]-mu)*rs*gv[nt] + lv[nt];
      s3 += zn*wv[nt];
    }
    #pragma unroll
    for (int m=1;m<16;m<<=1) s3 += __shfl_xor(s3,m);
    if (l15 == 0) llog[16*w + quad*4 + r] = s3 + b2v;
  }
  __syncthreads();

  // ---- phase 2: topk/softmax per node (threads 0..3), plain stores only ----
  if (t < 4){
    int n = blockIdx.x*4 + t;
    float l[CCC];
    #pragma unroll
    for (int c=0;c<CCC;++c) l[c] = llog[t*16+c];
    unsigned mask = 0;
    #pragma unroll
    for (int k=0;k<KTOP;++k){
      float best = -3e38f; int bi = 0;
      #pragma unroll
      for (int c=0;c<CCC;++c){
        bool taken = (mask>>c)&1u;
        if (!taken && l[c] > best){ best = l[c]; bi = c; }
      }
      mask |= 1u<<bi;
    }
    float m = -3e38f;
    #pragma unroll
    for (int c=0;c<CCC;++c) m = l[c]>m ? l[c] : m;
    float s = 0.f;
    #pragma unroll
    for (int c=0;c<CCC;++c) s += expf(l[c]-m);
    float inv = 1.0f/s;
    unsigned m2 = mask;
    for (int j=0;j<KTOP;++j){
      int ci = __ffs(m2)-1; m2 &= m2-1u;
      unsigned rest = mask & ~(1u<<ci);
      int v[3]; unsigned r2 = rest;
      #pragma unroll
      for (int q=0;q<3;++q){ int col = __ffs(r2)-1; r2 &= r2-1u; v[q] = col - (col>ci ? 1:0); }
      int rank = C3i(v[2]) + C2i(v[1]) + v[0];
      int e4 = n*KTOP + j;
      cols[e4] = ci; ranks[e4] = rank; fiSel[e4] = expf(l[ci]-m)*inv;
    }
  }
}

// ===== stage C: class feature sums (high-TLP atomics, 6144 blocks) + nodeList
// ===== build in 12 extra blocks (merged k_nlist; R10-proven) =====
__global__ __launch_bounds__(256) void k_accF(const float* __restrict__ X,
    const int* __restrict__ cols, const int* __restrict__ ranks,
    const float* __restrict__ fiSel, float* __restrict__ F, float* __restrict__ cnt,
    int* __restrict__ nodeCnt, int* __restrict__ nodeList){
  __shared__ int lcnt[CCC];
  __shared__ int lbase[CCC];
  int t = threadIdx.x;
  if (blockIdx.x < NN*KTOP/2){
    int e = blockIdx.x*2 + (t>>7);
    int h = t & 127;
    int ci = cols[e], rank = ranks[e];
    float fi = fiSel[e];
    int n = e >> 2;
    float v = X[(n*CCC+ci)*HH + h] * fi;
    atomicAdd(&F[(ci*NCLS+rank)*HH + h], v);
    if (h==0) atomicAdd(&cnt[ci*NCLS+rank], 1.0f);
  } else {
    int nb = blockIdx.x - NN*KTOP/2;   // 0..11
    if (t < CCC) lcnt[t] = 0;
    __syncthreads();
    int n = nb*256 + t;
    int mycis[KTOP], mypos[KTOP];
    #pragma unroll
    for (int j=0;j<KTOP;++j){
      int ci = cols[n*KTOP+j];
      mycis[j] = ci;
      mypos[j] = atomicAdd(&lcnt[ci], 1);
    }
    __syncthreads();
    if (t < CCC) lbase[t] = atomicAdd(&nodeCnt[t*16], lcnt[t]);
    __syncthreads();
    #pragma unroll
    for (int j=0;j<KTOP;++j){
      int ci = mycis[j];
      nodeList[ci*NN + lbase[ci] + mypos[j]] = n*KTOP + j;
    }
  }
}

// ====== stage D: pairs + singles + degrees + inclusion-exclusion agg (R1-proven) ======
__global__ __launch_bounds__(256) void k_graph(const float* __restrict__ F,
    const float* __restrict__ cnt, float* __restrict__ agg){
  int cb = blockIdx.x, ci = blockIdx.y, t = threadIdx.x;
  __shared__ float cntl[NCLS];
  __shared__ float PcS[105], UcS[15];
  __shared__ int   abcs[NCLS];   // a | b<<5 | c<<10
  __shared__ int   prs[NCLS];    // pab | pac<<10 | pbc<<20
  __shared__ float Fl[NCLS*GCP];
  __shared__ float P[105*GCP];
  __shared__ float U[15*GCP];
  const float* Fc = F + (size_t)ci*NCLS*HH + cb*GCP;

  for (int i=t; i<NCLS*2; i+=256){
    int r = i>>1, hf = i&1;
    float4 v = *(const float4*)(Fc + (size_t)r*HH + hf*4);
    *(float4*)(&Fl[r*GCP + hf*4]) = v;
  }
  for (int r=t; r<NCLS; r+=256){
    cntl[r] = cnt[ci*NCLS+r];
    int c=2; while (c<14 && C3i(c+1)<=r) c++;
    int rem = r - C3i(c);
    int b=1; while (b<c-1 && C2i(b+1)<=rem) b++;
    int a = rem - C2i(b);
    abcs[r] = a | (b<<5) | (c<<10);
    prs[r] = (C2i(b)+a) | ((C2i(c)+a)<<10) | ((C2i(c)+b)<<20);
  }
  __syncthreads();
  if (t<105){
    int pb=1; while (pb<14 && C2i(pb+1)<=t) pb++;
    int pa = t - C2i(pb);
    float s=0.f;
    #pragma unroll
    for (int z=0;z<15;++z){
      if (z==pa||z==pb) continue;
      int lo,mid,hi;
      if (z<pa){lo=z;mid=pa;hi=pb;} else if (z<pb){lo=pa;mid=z;hi=pb;} else {lo=pa;mid=pb;hi=z;}
      s += cntl[C3i(hi)+C2i(mid)+lo];
    }
    PcS[t]=s;
  }
  __syncthreads();
  if (t<15){
    float s=0.f;
    #pragma unroll
    for (int y=0;y<15;++y){
      if (y==t) continue;
      int lo = t<y?t:y, hi = t<y?y:t;
      s += PcS[C2i(hi)+lo];
    }
    UcS[t]=0.5f*s;
  }
  __syncthreads();
  for (int idx=t; idx<105*GCP; idx+=256){
    int p = idx/GCP, col = idx&(GCP-1);
    int pb=1; while (pb<14 && C2i(pb+1)<=p) pb++;
    int pa = p - C2i(pb);
    float s=0.f;
    #pragma unroll
    for (int z=0;z<15;++z){
      if (z==pa||z==pb) continue;
      int lo,mid,hi;
      if (z<pa){lo=z;mid=pa;hi=pb;} else if (z<pb){lo=pa;mid=z;hi=pb;} else {lo=pa;mid=pb;hi=z;}
      s += Fl[(C3i(hi)+C2i(mid)+lo)*GCP + col];
    }
    P[idx]=s;
  }
  __syncthreads();
  for (int idx=t; idx<15*GCP; idx+=256){
    int x = idx/GCP, col = idx&(GCP-1);
    float s=0.f;
    #pragma unroll
    for (int y=0;y<15;++y){
      if (y==x) continue;
      int lo = x<y?x:y, hi = x<y?y:x;
      s += P[(C2i(hi)+lo)*GCP + col];
    }
    U[idx]=0.5f*s;
  }
  __syncthreads();
  for (int idx=t; idx<NCLS*GCP; idx+=256){
    int r = idx/GCP, col = idx&(GCP-1);
    int v1=abcs[r]; int a=v1&31,b=(v1>>5)&31,c=(v1>>10)&31;
    int v2=prs[r];  int pab=v2&1023,pac=(v2>>10)&1023,pbc=(v2>>20)&1023;
    float deg = UcS[a]+UcS[b]+UcS[c]-PcS[pab]-PcS[pac]-PcS[pbc]+cntl[r];
    float invd = 1.0f/fmaxf(deg,1.0f);
    float v = U[a*GCP+col]+U[b*GCP+col]+U[c*GCP+col]
            - P[pab*GCP+col]-P[pac*GCP+col]-P[pbc*GCP+col]
            + Fl[r*GCP+col];
    agg[(size_t)ci*NCLS*HH + (size_t)r*HH + cb*GCP + col] = v*invd;
  }
}

// ===== stage E (merged E1+E2): hc = relu(agg[rank]@Wl^T + bl + fi*X @ Wr^T) =====
// Two MFMAs into ONE f32 accumulator; k_aggwl dispatch + agg in-place round trip
// eliminated. agg->f16 quantization identical to the old k_aggwl A-operand cvt.
__global__ __launch_bounds__(256) void k_hc2(const float* __restrict__ X,
    const float* __restrict__ agg,
    const _Float16* __restrict__ Wlh, const _Float16* __restrict__ Wrh,
    const float* __restrict__ bl,
    const int* __restrict__ ranks, const float* __restrict__ fiSel,
    const int* __restrict__ nodeCnt, const int* __restrict__ nodeList,
    float* __restrict__ hcBuf, float* __restrict__ sums){
  int ci = blockIdx.y;
  int cntc = nodeCnt[ci*16];
  int base = blockIdx.x * MT;
  if (base >= cntc) return;
  __shared__ float rb[8];
  int t = threadIdx.x;
  int w = t >> 6;
  int lane = t & 63;
  int l15 = lane & 15, quad = lane >> 4;

  int pA = base + 16*w + l15;
  float fi = 0.f; int nA = 0; int rkA = -1;
  if (pA < cntc){
    int e = nodeList[ci*NN + pA];
    fi = fiSel[e]; nA = e >> 2; rkA = ranks[e];
  }
  // A-operand 1: fi * X[nA, ci, :]
  const float* xrow = X + ((size_t)nA*CCC + ci)*HH;
  h8 af[4];
  #pragma unroll
  for (int c=0;c<4;++c){
    float4 u = *(const float4*)(xrow + c*32 + quad*8);
    float4 v = *(const float4*)(xrow + c*32 + quad*8 + 4);
    float xv[8] = {u.x,u.y,u.z,u.w,v.x,v.y,v.z,v.w};
    #pragma unroll
    for (int j=0;j<8;++j) af[c][j] = (_Float16)(xv[j]*fi);
  }
  // A-operand 2: agg[ci, rank(pA), :]  (zero for inactive rows)
  h8 ag[4];
  if (rkA >= 0){
    const float* arow = agg + ((size_t)ci*NCLS + rkA)*HH;
    #pragma unroll
    for (int c=0;c<4;++c){
      float4 u = *(const float4*)(arow + c*32 + quad*8);
      float4 v = *(const float4*)(arow + c*32 + quad*8 + 4);
      float xv[8] = {u.x,u.y,u.z,u.w,v.x,v.y,v.z,v.w};
      #pragma unroll
      for (int j=0;j<8;++j) ag[c][j] = (_Float16)xv[j];
    }
  } else {
    #pragma unroll
    for (int c=0;c<4;++c) ag[c] = (h8){0,0,0,0,0,0,0,0};
  }

  f4 acc[8];
  #pragma unroll
  for (int nt=0;nt<8;++nt) acc[nt] = (f4){0.f,0.f,0.f,0.f};

  const _Float16* WcR = Wrh + (size_t)ci*HH*HH;
  const _Float16* WcL = Wlh + (size_t)ci*HH*HH;
  #pragma unroll
  for (int c=0;c<4;++c){
    #pragma unroll
    for (int nt=0;nt<8;++nt){
      int o = nt*16 + l15;
      h8 br = *(const h8*)(WcR + (size_t)o*HH + c*32 + quad*8);
      h8 blf= *(const h8*)(WcL + (size_t)o*HH + c*32 + quad*8);
      acc[nt] = __builtin_amdgcn_mfma_f32_16x16x32_f16(af[c], br,  acc[nt], 0,0,0);
      acc[nt] = __builtin_amdgcn_mfma_f32_16x16x32_f16(ag[c], blf, acc[nt], 0,0,0);
    }
  }

  float s1 = 0.f, s2 = 0.f;
  #pragma unroll
  for (int r=0;r<4;++r){
    int pD = base + 16*w + quad*4 + r;
    int e2 = -1;
    if (pD < cntc) e2 = nodeList[ci*NN + pD];
    if (e2 >= 0){
      float* drow = hcBuf + (size_t)e2*HH;
      #pragma unroll
      for (int nt=0;nt<8;++nt){
        int o = nt*16 + l15;
        float vv = acc[nt][r] + bl[ci*HH + o];
        vv = vv>0.f ? vv : 0.f;
        drow[o] = vv;
        s1 += vv; s2 += vv*vv;
      }
    }
  }
  #pragma unroll
  for (int m=1;m<64;m<<=1){ s1 += __shfl_xor(s1,m); s2 += __shfl_xor(s2,m); }
  if (lane == 0){ rb[w] = s1; rb[4+w] = s2; }
  __syncthreads();
  if (t==0){
    atomicAdd(&sums[ci],    rb[0]+rb[1]+rb[2]+rb[3]);
    atomicAdd(&sums[16+ci], rb[4]+rb[5]+rb[6]+rb[7]);
  }
}

// ========== stage F: masked mean/var normalize, write output ==========
__global__ __launch_bounds__(256) void k_out(const float* __restrict__ hcBuf,
    const int* __restrict__ cols, const int* __restrict__ nodeCnt,
    const float* __restrict__ sums, float* __restrict__ out){
  int idx = blockIdx.x*256 + threadIdx.x;
  int e = idx >> 7;
  int ci = cols[e];
  float cntf = (float)nodeCnt[ci*16];
  float nel = fmaxf(cntf * (float)HH, 1.0f);
  float mu = sums[ci]/nel;
  float var = sums[16+ci]/nel - mu*mu;
  out[idx] = (hcBuf[idx]-mu)/sqrtf(var+EPSF);
}

extern "C" void kernel_launch(void* const* d_in, const int* in_sizes, int n_in,
                              void* d_out, int out_size, void* d_ws, size_t ws_size,
                              hipStream_t stream){
  const float* X    = (const float*)d_in[0];
  const float* W1   = (const float*)d_in[1];
  const float* b1   = (const float*)d_in[2];
  const float* ln_g = (const float*)d_in[3];
  const float* ln_b = (const float*)d_in[4];
  const float* W2   = (const float*)d_in[5];
  const float* b2   = (const float*)d_in[6];
  const float* Wl   = (const float*)d_in[7];
  const float* bl   = (const float*)d_in[8];
  const float* Wr   = (const float*)d_in[9];
  float* ws = (float*)d_ws;
  float* F      = ws + OFF_F;
  float* cnt    = ws + OFF_CNT;
  float* sums   = ws + OFF_SUMS;
  int*   nodeCnt= (int*)(ws + OFF_NCNT);
  int*   cols   = (int*)(ws + OFF_COLS);
  int*   ranks  = (int*)(ws + OFF_RANKS);
  float* fiSel  = ws + OFF_FISEL;
  int*   nodeList=(int*)(ws + OFF_NLIST);
  float* agg    = ws + OFF_AGG;
  float* hcBuf  = ws + OFF_HC;
  _Float16* hbase = (_Float16*)(ws + OFF_HALF);
  float* out    = (float*)d_out;

  k_fused  <<<dim3(NN*CCC/MT), dim3(256), 0, stream>>>(X, W1, b1, ln_g, ln_b, W2, b2,
                                                       Wl, Wr, hbase, F, ws,
                                                       cols, ranks, fiSel);
  k_accF   <<<dim3(NN*KTOP/2 + 12), dim3(256), 0, stream>>>(X, cols, ranks, fiSel, F, cnt,
                                                            nodeCnt, nodeList);
  k_graph  <<<dim3(GCB,16), dim3(256), 0, stream>>>(F, cnt, agg);
  k_hc2    <<<dim3((NN/MT),16), dim3(256), 0, stream>>>(X, agg, hbase+HOFF_WLH,
                                                        hbase+HOFF_WRH, bl, ranks, fiSel,
                                                        nodeCnt, nodeList, hcBuf, sums);
  k_out    <<<dim3(NN*KTOP*HH/256), dim3(256), 0, stream>>>(hcBuf, cols, nodeCnt, sums, out);
}

// Round 12
// 153.798 us; speedup vs baseline: 3.8139x; 1.0516x over previous
//
#include <hip/hip_runtime.h>

#define NN 3072
#define CCC 16
#define HH 128
#define KTOP 4
#define NCLS 455   // C(15,3)
#define EPSF 1e-5f

// ---------------- ws layout (float offsets) ----------------
#define OFF_F       0
#define SZ_F        (16*NCLS*HH)            // 931840
#define OFF_CNT     (OFF_F + SZ_F)
#define SZ_CNT      (16*NCLS)
#define OFF_SUMS    (OFF_CNT + SZ_CNT)
#define SZ_SUMS     32
#define OFF_NCNT    (OFF_SUMS + SZ_SUMS)    // int nodeCnt[16*16]
#define SZ_NCNT     256
#define SMALL_ZERO  (SZ_CNT + SZ_SUMS + SZ_NCNT)  // cnt+sums+nodeCnt (zeroed by k_fused blk0)
#define OFF_COLS    (OFF_NCNT + SZ_NCNT)
#define SZ_E        (NN*KTOP)
#define OFF_RANKS   (OFF_COLS + SZ_E)
#define OFF_FISEL   (OFF_RANKS + SZ_E)
#define OFF_NLIST   (OFF_FISEL + SZ_E)
#define SZ_NLIST    (16*NN)
#define OFF_AGG     (OFF_NLIST + SZ_NLIST)
#define OFF_HC      (OFF_AGG + SZ_F)
#define SZ_HC       (NN*KTOP*HH)
#define OFF_HALF    (OFF_HC + SZ_HC)
#define HOFF_WLH    0
#define HOFF_WRH    262144

#define MT 64              // rows per block for k_hc2
#define FMT 128            // rows per block for k_fused (512 threads, 8 nodes)
#define FBLK (NN*CCC/FMT)  // 384 blocks
#define GCP 8              // k_graph cols per block
#define GCB (HH/GCP)
#define W1P 132            // padded row stride (f16) for W1 LDS: 2-way bank aliasing only

typedef _Float16 h8 __attribute__((ext_vector_type(8)));
typedef float    f4 __attribute__((ext_vector_type(4)));

__device__ __forceinline__ int C2i(int x){ return x*(x-1)/2; }
__device__ __forceinline__ int C3i(int x){ return x*(x-1)*(x-2)/6; }

// ===== stage A+B fused: 512 thr / 128 rows per block. W1->LDS hi/lo cvt (amortized
// ===== 2x vs R11), logits MFMA, in-LDS topk/softmax. X-load hoisted above cvt.
// ===== Folded: F zeroing, Wl/Wr f16 cvt, small-zero (blk 0).
__global__ __launch_bounds__(512) void k_fused(const float* __restrict__ X,
    const float* __restrict__ W1,
    const float* __restrict__ b1, const float* __restrict__ ln_g,
    const float* __restrict__ ln_b, const float* __restrict__ W2,
    const float* __restrict__ b2,
    const float* __restrict__ Wl, const float* __restrict__ Wr,
    _Float16* __restrict__ hbase, float* __restrict__ F, float* __restrict__ ws,
    int* __restrict__ cols, int* __restrict__ ranks, float* __restrict__ fiSel){
  __shared__ _Float16 w1h_s[HH*W1P];
  __shared__ _Float16 w1l_s[HH*W1P];
  __shared__ float llog[FMT];
  int t = threadIdx.x;
  int w = t >> 6;              // wave 0..7 -> rows 16w..16w+15 (node w)
  int lane = t & 63;
  int l15 = lane & 15, quad = lane >> 4;
  int base = blockIdx.x * FMT;
  int mA = base + 16*w + l15;

  // ---- X rows first: HBM latency hides under the W1-cvt loop below ----
  const float* xrow = X + (size_t)mA*HH;
  float4 xu[4], xv[4];
  #pragma unroll
  for (int c=0;c<4;++c){
    xu[c] = *(const float4*)(xrow + c*32 + quad*8);
    xv[c] = *(const float4*)(xrow + c*32 + quad*8 + 4);
  }

  // ---- W1 -> LDS f16 hi/lo (same values as before; 32 iters/thread) ----
  for (int j = t; j < HH*HH; j += 512){
    int r = j >> 7, c0 = j & 127;
    float x = W1[j];
    _Float16 h = (_Float16)x;
    w1h_s[r*W1P + c0] = h;
    w1l_s[r*W1P + c0] = (_Float16)(x - (float)h);
  }

  // ---- folded housekeeping: zero F + cvt Wl/Wr + (blk 0) small zeros ----
  {
    f4 z4 = (f4){0.f,0.f,0.f,0.f};
    for (int i = blockIdx.x*512 + t; i < SZ_F/4; i += FBLK*512)
      *(f4*)(F + (size_t)i*4) = z4;
    for (int i = blockIdx.x*512 + t; i < 2*262144; i += FBLK*512){
      if (i < 262144) hbase[HOFF_WLH + i] = (_Float16)Wl[i];
      else            hbase[HOFF_WRH + (i-262144)] = (_Float16)Wr[i-262144];
    }
    if (blockIdx.x == 0)
      for (int i = t; i < SMALL_ZERO; i += 512) ws[OFF_CNT + i] = 0.f;
  }

  // ---- phase 1: z=relu(X@W1^T+b1); LN; logit=zn.W2+b2 (identical math) ----
  h8 ah[4], al[4];
  #pragma unroll
  for (int c=0;c<4;++c){
    float xvv[8] = {xu[c].x,xu[c].y,xu[c].z,xu[c].w,xv[c].x,xv[c].y,xv[c].z,xv[c].w};
    #pragma unroll
    for (int j=0;j<8;++j){
      _Float16 hi = (_Float16)xvv[j];
      ah[c][j] = hi;
      al[c][j] = (_Float16)(xvv[j] - (float)hi);
    }
  }
  __syncthreads();   // W1 LDS ready

  f4 acc[8];
  #pragma unroll
  for (int nt=0;nt<8;++nt) acc[nt] = (f4){0.f,0.f,0.f,0.f};

  #pragma unroll
  for (int c=0;c<4;++c){
    #pragma unroll
    for (int nt=0;nt<8;++nt){
      int o = nt*16 + l15;
      h8 bh  = *(const h8*)(w1h_s + o*W1P + c*32 + quad*8);
      h8 bl_ = *(const h8*)(w1l_s + o*W1P + c*32 + quad*8);
      acc[nt] = __builtin_amdgcn_mfma_f32_16x16x32_f16(ah[c], bh,  acc[nt], 0,0,0);
      acc[nt] = __builtin_amdgcn_mfma_f32_16x16x32_f16(al[c], bh,  acc[nt], 0,0,0);
      acc[nt] = __builtin_amdgcn_mfma_f32_16x16x32_f16(ah[c], bl_, acc[nt], 0,0,0);
      acc[nt] = __builtin_amdgcn_mfma_f32_16x16x32_f16(al[c], bl_, acc[nt], 0,0,0);
    }
  }

  float bv[8], gv[8], lv[8], wv[8];
  #pragma unroll
  for (int nt=0;nt<8;++nt){
    int o = nt*16 + l15;
    bv[nt]=b1[o]; gv[nt]=ln_g[o]; lv[nt]=ln_b[o]; wv[nt]=W2[o];
  }
  float b2v = b2[0];
  #pragma unroll
  for (int r=0;r<4;++r){
    float z[8];
    float s1=0.f, s2=0.f;
    #pragma unroll
    for (int nt=0;nt<8;++nt){
      float zz = acc[nt][r] + bv[nt];
      zz = zz>0.f ? zz : 0.f;
      z[nt] = zz; s1 += zz; s2 += zz*zz;
    }
    #pragma unroll
    for (int m=1;m<16;m<<=1){ s1 += __shfl_xor(s1,m); s2 += __shfl_xor(s2,m); }
    float mu = s1/(float)HH;
    float var = s2/(float)HH - mu*mu;
    float rs = 1.0f/sqrtf(var+EPSF);
    float s3 = 0.f;
    #pragma unroll
    for (int nt=0;nt<8;++nt){
      float zn = (z[nt]-mu)*rs*gv[nt] + lv[nt];
      s3 += zn*wv[nt];
    }
    #pragma unroll
    for (int m=1;m<16;m<<=1) s3 += __shfl_xor(s3,m);
    if (l15 == 0) llog[16*w + quad*4 + r] = s3 + b2v;
  }
  __syncthreads();

  // ---- phase 2: topk/softmax per node (threads 0..7), plain stores only ----
  if (t < 8){
    int n = blockIdx.x*8 + t;
    float l[CCC];
    #pragma unroll
    for (int c=0;c<CCC;++c) l[c] = llog[t*16+c];
    unsigned mask = 0;
    #pragma unroll
    for (int k=0;k<KTOP;++k){
      float best = -3e38f; int bi = 0;
      #pragma unroll
      for (int c=0;c<CCC;++c){
        bool taken = (mask>>c)&1u;
        if (!taken && l[c] > best){ best = l[c]; bi = c; }
      }
      mask |= 1u<<bi;
    }
    float m = -3e38f;
    #pragma unroll
    for (int c=0;c<CCC;++c) m = l[c]>m ? l[c] : m;
    float s = 0.f;
    #pragma unroll
    for (int c=0;c<CCC;++c) s += expf(l[c]-m);
    float inv = 1.0f/s;
    unsigned m2 = mask;
    for (int j=0;j<KTOP;++j){
      int ci = __ffs(m2)-1; m2 &= m2-1u;
      unsigned rest = mask & ~(1u<<ci);
      int v[3]; unsigned r2 = rest;
      #pragma unroll
      for (int q=0;q<3;++q){ int col = __ffs(r2)-1; r2 &= r2-1u; v[q] = col - (col>ci ? 1:0); }
      int rank = C3i(v[2]) + C2i(v[1]) + v[0];
      int e4 = n*KTOP + j;
      cols[e4] = ci; ranks[e4] = rank; fiSel[e4] = expf(l[ci]-m)*inv;
    }
  }
}

// ===== stage C: class feature sums (high-TLP atomics, 6144 blocks) + nodeList
// ===== build in 12 extra blocks (merged k_nlist; R10-proven) =====
__global__ __launch_bounds__(256) void k_accF(const float* __restrict__ X,
    const int* __restrict__ cols, const int* __restrict__ ranks,
    const float* __restrict__ fiSel, float* __restrict__ F, float* __restrict__ cnt,
    int* __restrict__ nodeCnt, int* __restrict__ nodeList){
  __shared__ int lcnt[CCC];
  __shared__ int lbase[CCC];
  int t = threadIdx.x;
  if (blockIdx.x < NN*KTOP/2){
    int e = blockIdx.x*2 + (t>>7);
    int h = t & 127;
    int ci = cols[e], rank = ranks[e];
    float fi = fiSel[e];
    int n = e >> 2;
    float v = X[(n*CCC+ci)*HH + h] * fi;
    atomicAdd(&F[(ci*NCLS+rank)*HH + h], v);
    if (h==0) atomicAdd(&cnt[ci*NCLS+rank], 1.0f);
  } else {
    int nb = blockIdx.x - NN*KTOP/2;   // 0..11
    if (t < CCC) lcnt[t] = 0;
    __syncthreads();
    int n = nb*256 + t;
    int mycis[KTOP], mypos[KTOP];
    #pragma unroll
    for (int j=0;j<KTOP;++j){
      int ci = cols[n*KTOP+j];
      mycis[j] = ci;
      mypos[j] = atomicAdd(&lcnt[ci], 1);
    }
    __syncthreads();
    if (t < CCC) lbase[t] = atomicAdd(&nodeCnt[t*16], lcnt[t]);
    __syncthreads();
    #pragma unroll
    for (int j=0;j<KTOP;++j){
      int ci = mycis[j];
      nodeList[ci*NN + lbase[ci] + mypos[j]] = n*KTOP + j;
    }
  }
}

// ====== stage D: pairs + singles + degrees + inclusion-exclusion agg (R1-proven) ======
__global__ __launch_bounds__(256) void k_graph(const float* __restrict__ F,
    const float* __restrict__ cnt, float* __restrict__ agg){
  int cb = blockIdx.x, ci = blockIdx.y, t = threadIdx.x;
  __shared__ float cntl[NCLS];
  __shared__ float PcS[105], UcS[15];
  __shared__ int   abcs[NCLS];   // a | b<<5 | c<<10
  __shared__ int   prs[NCLS];    // pab | pac<<10 | pbc<<20
  __shared__ float Fl[NCLS*GCP];
  __shared__ float P[105*GCP];
  __shared__ float U[15*GCP];
  const float* Fc = F + (size_t)ci*NCLS*HH + cb*GCP;

  for (int i=t; i<NCLS*2; i+=256){
    int r = i>>1, hf = i&1;
    float4 v = *(const float4*)(Fc + (size_t)r*HH + hf*4);
    *(float4*)(&Fl[r*GCP + hf*4]) = v;
  }
  for (int r=t; r<NCLS; r+=256){
    cntl[r] = cnt[ci*NCLS+r];
    int c=2; while (c<14 && C3i(c+1)<=r) c++;
    int rem = r - C3i(c);
    int b=1; while (b<c-1 && C2i(b+1)<=rem) b++;
    int a = rem - C2i(b);
    abcs[r] = a | (b<<5) | (c<<10);
    prs[r] = (C2i(b)+a) | ((C2i(c)+a)<<10) | ((C2i(c)+b)<<20);
  }
  __syncthreads();
  if (t<105){
    int pb=1; while (pb<14 && C2i(pb+1)<=t) pb++;
    int pa = t - C2i(pb);
    float s=0.f;
    #pragma unroll
    for (int z=0;z<15;++z){
      if (z==pa||z==pb) continue;
      int lo,mid,hi;
      if (z<pa){lo=z;mid=pa;hi=pb;} else if (z<pb){lo=pa;mid=z;hi=pb;} else {lo=pa;mid=pb;hi=z;}
      s += cntl[C3i(hi)+C2i(mid)+lo];
    }
    PcS[t]=s;
  }
  __syncthreads();
  if (t<15){
    float s=0.f;
    #pragma unroll
    for (int y=0;y<15;++y){
      if (y==t) continue;
      int lo = t<y?t:y, hi = t<y?y:t;
      s += PcS[C2i(hi)+lo];
    }
    UcS[t]=0.5f*s;
  }
  __syncthreads();
  for (int idx=t; idx<105*GCP; idx+=256){
    int p = idx/GCP, col = idx&(GCP-1);
    int pb=1; while (pb<14 && C2i(pb+1)<=p) pb++;
    int pa = p - C2i(pb);
    float s=0.f;
    #pragma unroll
    for (int z=0;z<15;++z){
      if (z==pa||z==pb) continue;
      int lo,mid,hi;
      if (z<pa){lo=z;mid=pa;hi=pb;} else if (z<pb){lo=pa;mid=z;hi=pb;} else {lo=pa;mid=pb;hi=z;}
      s += Fl[(C3i(hi)+C2i(mid)+lo)*GCP + col];
    }
    P[idx]=s;
  }
  __syncthreads();
  for (int idx=t; idx<15*GCP; idx+=256){
    int x = idx/GCP, col = idx&(GCP-1);
    float s=0.f;
    #pragma unroll
    for (int y=0;y<15;++y){
      if (y==x) continue;
      int lo = x<y?x:y, hi = x<y?y:x;
      s += P[(C2i(hi)+lo)*GCP + col];
    }
    U[idx]=0.5f*s;
  }
  __syncthreads();
  for (int idx=t; idx<NCLS*GCP; idx+=256){
    int r = idx/GCP, col = idx&(GCP-1);
    int v1=abcs[r]; int a=v1&31,b=(v1>>5)&31,c=(v1>>10)&31;
    int v2=prs[r];  int pab=v2&1023,pac=(v2>>10)&1023,pbc=(v2>>20)&1023;
    float deg = UcS[a]+UcS[b]+UcS[c]-PcS[pab]-PcS[pac]-PcS[pbc]+cntl[r];
    float invd = 1.0f/fmaxf(deg,1.0f);
    float v = U[a*GCP+col]+U[b*GCP+col]+U[c*GCP+col]
            - P[pab*GCP+col]-P[pac*GCP+col]-P[pbc*GCP+col]
            + Fl[r*GCP+col];
    agg[(size_t)ci*NCLS*HH + (size_t)r*HH + cb*GCP + col] = v*invd;
  }
}

// ===== stage E (merged E1+E2): hc = relu(agg[rank]@Wl^T + bl + fi*X @ Wr^T) =====
__global__ __launch_bounds__(256) void k_hc2(const float* __restrict__ X,
    const float* __restrict__ agg,
    const _Float16* __restrict__ Wlh, const _Float16* __restrict__ Wrh,
    const float* __restrict__ bl,
    const int* __restrict__ ranks, const float* __restrict__ fiSel,
    const int* __restrict__ nodeCnt, const int* __restrict__ nodeList,
    float* __restrict__ hcBuf, float* __restrict__ sums){
  int ci = blockIdx.y;
  int cntc = nodeCnt[ci*16];
  int base = blockIdx.x * MT;
  if (base >= cntc) return;
  __shared__ float rb[8];
  int t = threadIdx.x;
  int w = t >> 6;
  int lane = t & 63;
  int l15 = lane & 15, quad = lane >> 4;

  int pA = base + 16*w + l15;
  float fi = 0.f; int nA = 0; int rkA = -1;
  if (pA < cntc){
    int e = nodeList[ci*NN + pA];
    fi = fiSel[e]; nA = e >> 2; rkA = ranks[e];
  }
  // A-operand 1: fi * X[nA, ci, :]
  const float* xrow = X + ((size_t)nA*CCC + ci)*HH;
  h8 af[4];
  #pragma unroll
  for (int c=0;c<4;++c){
    float4 u = *(const float4*)(xrow + c*32 + quad*8);
    float4 v = *(const float4*)(xrow + c*32 + quad*8 + 4);
    float xv[8] = {u.x,u.y,u.z,u.w,v.x,v.y,v.z,v.w};
    #pragma unroll
    for (int j=0;j<8;++j) af[c][j] = (_Float16)(xv[j]*fi);
  }
  // A-operand 2: agg[ci, rank(pA), :]  (zero for inactive rows)
  h8 ag[4];
  if (rkA >= 0){
    const float* arow = agg + ((size_t)ci*NCLS + rkA)*HH;
    #pragma unroll
    for (int c=0;c<4;++c){
      float4 u = *(const float4*)(arow + c*32 + quad*8);
      float4 v = *(const float4*)(arow + c*32 + quad*8 + 4);
      float xv[8] = {u.x,u.y,u.z,u.w,v.x,v.y,v.z,v.w};
      #pragma unroll
      for (int j=0;j<8;++j) ag[c][j] = (_Float16)xv[j];
    }
  } else {
    #pragma unroll
    for (int c=0;c<4;++c) ag[c] = (h8){0,0,0,0,0,0,0,0};
  }

  f4 acc[8];
  #pragma unroll
  for (int nt=0;nt<8;++nt) acc[nt] = (f4){0.f,0.f,0.f,0.f};

  const _Float16* WcR = Wrh + (size_t)ci*HH*HH;
  const _Float16* WcL = Wlh + (size_t)ci*HH*HH;
  #pragma unroll
  for (int c=0;c<4;++c){
    #pragma unroll
    for (int nt=0;nt<8;++nt){
      int o = nt*16 + l15;
      h8 br = *(const h8*)(WcR + (size_t)o*HH + c*32 + quad*8);
      h8 blf= *(const h8*)(WcL + (size_t)o*HH + c*32 + quad*8);
      acc[nt] = __builtin_amdgcn_mfma_f32_16x16x32_f16(af[c], br,  acc[nt], 0,0,0);
      acc[nt] = __builtin_amdgcn_mfma_f32_16x16x32_f16(ag[c], blf, acc[nt], 0,0,0);
    }
  }

  float s1 = 0.f, s2 = 0.f;
  #pragma unroll
  for (int r=0;r<4;++r){
    int pD = base + 16*w + quad*4 + r;
    int e2 = -1;
    if (pD < cntc) e2 = nodeList[ci*NN + pD];
    if (e2 >= 0){
      float* drow = hcBuf + (size_t)e2*HH;
      #pragma unroll
      for (int nt=0;nt<8;++nt){
        int o = nt*16 + l15;
        float vv = acc[nt][r] + bl[ci*HH + o];
        vv = vv>0.f ? vv : 0.f;
        drow[o] = vv;
        s1 += vv; s2 += vv*vv;
      }
    }
  }
  #pragma unroll
  for (int m=1;m<64;m<<=1){ s1 += __shfl_xor(s1,m); s2 += __shfl_xor(s2,m); }
  if (lane == 0){ rb[w] = s1; rb[4+w] = s2; }
  __syncthreads();
  if (t==0){
    atomicAdd(&sums[ci],    rb[0]+rb[1]+rb[2]+rb[3]);
    atomicAdd(&sums[16+ci], rb[4]+rb[5]+rb[6]+rb[7]);
  }
}

// ========== stage F: masked mean/var normalize, write output ==========
__global__ __launch_bounds__(256) void k_out(const float* __restrict__ hcBuf,
    const int* __restrict__ cols, const int* __restrict__ nodeCnt,
    const float* __restrict__ sums, float* __restrict__ out){
  int idx = blockIdx.x*256 + threadIdx.x;
  int e = idx >> 7;
  int ci = cols[e];
  float cntf = (float)nodeCnt[ci*16];
  float nel = fmaxf(cntf * (float)HH, 1.0f);
  float mu = sums[ci]/nel;
  float var = sums[16+ci]/nel - mu*mu;
  out[idx] = (hcBuf[idx]-mu)/sqrtf(var+EPSF);
}

extern "C" void kernel_launch(void* const* d_in, const int* in_sizes, int n_in,
                              void* d_out, int out_size, void* d_ws, size_t ws_size,
                              hipStream_t stream){
  const float* X    = (const float*)d_in[0];
  const float* W1   = (const float*)d_in[1];
  const float* b1   = (const float*)d_in[2];
  const float* ln_g = (const float*)d_in[3];
  const float* ln_b = (const float*)d_in[4];
  const float* W2   = (const float*)d_in[5];
  const float* b2   = (const float*)d_in[6];
  const float* Wl   = (const float*)d_in[7];
  const float* bl   = (const float*)d_in[8];
  const float* Wr   = (const float*)d_in[9];
  float* ws = (float*)d_ws;
  float* F      = ws + OFF_F;
  float* cnt    = ws + OFF_CNT;
  float* sums   = ws + OFF_SUMS;
  int*   nodeCnt= (int*)(ws + OFF_NCNT);
  int*   cols   = (int*)(ws + OFF_COLS);
  int*   ranks  = (int*)(ws + OFF_RANKS);
  float* fiSel  = ws + OFF_FISEL;
  int*   nodeList=(int*)(ws + OFF_NLIST);
  float* agg    = ws + OFF_AGG;
  float* hcBuf  = ws + OFF_HC;
  _Float16* hbase = (_Float16*)(ws + OFF_HALF);
  float* out    = (float*)d_out;

  k_fused  <<<dim3(FBLK), dim3(512), 0, stream>>>(X, W1, b1, ln_g, ln_b, W2, b2,
                                                  Wl, Wr, hbase, F, ws,
                                                  cols, ranks, fiSel);
  k_accF   <<<dim3(NN*KTOP/2 + 12), dim3(256), 0, stream>>>(X, cols, ranks, fiSel, F, cnt,
                                                            nodeCnt, nodeList);
  k_graph  <<<dim3(GCB,16), dim3(256), 0, stream>>>(F, cnt, agg);
  k_hc2    <<<dim3((NN/MT),16), dim3(256), 0, stream>>>(X, agg, hbase+HOFF_WLH,
                                                        hbase+HOFF_WRH, bl, ranks, fiSel,
                                                        nodeCnt, nodeList, hcBuf, sums);
  k_out    <<<dim3(NN*KTOP*HH/256), dim3(256), 0, stream>>>(hcBuf, cols, nodeCnt, sums, out);
}

// Round 13
// 152.224 us; speedup vs baseline: 3.8533x; 1.0103x over previous
//
#include <hip/hip_runtime.h>

#define NN 3072
#define CCC 16
#define HH 128
#define KTOP 4
#define NCLS 455   // C(15,3)
#define EPSF 1e-5f

// ---------------- ws layout (float offsets) ----------------
#define OFF_F       0
#define SZ_F        (16*NCLS*HH)            // 931840
#define OFF_CNT     (OFF_F + SZ_F)
#define SZ_CNT      (16*NCLS)
#define OFF_SUMS    (OFF_CNT + SZ_CNT)
#define SZ_SUMS     32
#define OFF_NCNT    (OFF_SUMS + SZ_SUMS)    // int nodeCnt[16*16]
#define SZ_NCNT     256
#define SMALL_ZERO  (SZ_CNT + SZ_SUMS + SZ_NCNT)  // cnt+sums+nodeCnt (zeroed by k_fused blk0)
#define OFF_COLS    (OFF_NCNT + SZ_NCNT)
#define SZ_E        (NN*KTOP)
#define OFF_RANKS   (OFF_COLS + SZ_E)
#define OFF_FISEL   (OFF_RANKS + SZ_E)
#define OFF_NLIST   (OFF_FISEL + SZ_E)
#define SZ_NLIST    (16*NN)
#define OFF_AGG     (OFF_NLIST + SZ_NLIST)
#define OFF_HC      (OFF_AGG + SZ_F)
#define SZ_HC       (NN*KTOP*HH)
#define OFF_HALF    (OFF_HC + SZ_HC)
#define HOFF_WLH    0
#define HOFF_WRH    262144

#define MT 64              // rows per block for k_hc2
#define FTH 768            // k_fused threads (12 waves)
#define FMT 192            // rows per block for k_fused (12 nodes)
#define FBLK (NN*CCC/FMT)  // 256 blocks = exactly 1 per CU (no tail imbalance)
#define GCP 8              // k_graph cols per block
#define GCB (HH/GCP)
#define W1P 132            // padded row stride (f16) for W1 LDS: 2-way bank aliasing only

typedef _Float16 h8 __attribute__((ext_vector_type(8)));
typedef float    f4 __attribute__((ext_vector_type(4)));

__device__ __forceinline__ int C2i(int x){ return x*(x-1)/2; }
__device__ __forceinline__ int C3i(int x){ return x*(x-1)*(x-2)/6; }

// ===== stage A+B fused: 768 thr / 192 rows per block, grid=256 (1 block/CU,
// ===== balanced). W1->LDS hi/lo cvt, logits MFMA, in-LDS topk/softmax.
// ===== Folded: F zeroing, Wl/Wr f16 cvt, small-zero (blk 0).
__global__ __launch_bounds__(FTH) void k_fused(const float* __restrict__ X,
    const float* __restrict__ W1,
    const float* __restrict__ b1, const float* __restrict__ ln_g,
    const float* __restrict__ ln_b, const float* __restrict__ W2,
    const float* __restrict__ b2,
    const float* __restrict__ Wl, const float* __restrict__ Wr,
    _Float16* __restrict__ hbase, float* __restrict__ F, float* __restrict__ ws,
    int* __restrict__ cols, int* __restrict__ ranks, float* __restrict__ fiSel){
  __shared__ _Float16 w1h_s[HH*W1P];
  __shared__ _Float16 w1l_s[HH*W1P];
  __shared__ float llog[FMT];
  int t = threadIdx.x;
  int w = t >> 6;              // wave 0..11 -> rows 16w..16w+15 (node w)
  int lane = t & 63;
  int l15 = lane & 15, quad = lane >> 4;
  int base = blockIdx.x * FMT;
  int mA = base + 16*w + l15;

  // ---- X rows first: HBM latency hides under the W1-cvt loop below ----
  const float* xrow = X + (size_t)mA*HH;
  float4 xu[4], xv[4];
  #pragma unroll
  for (int c=0;c<4;++c){
    xu[c] = *(const float4*)(xrow + c*32 + quad*8);
    xv[c] = *(const float4*)(xrow + c*32 + quad*8 + 4);
  }

  // ---- W1 -> LDS f16 hi/lo (same values as before; 22 iters/thread) ----
  for (int j = t; j < HH*HH; j += FTH){
    int r = j >> 7, c0 = j & 127;
    float x = W1[j];
    _Float16 h = (_Float16)x;
    w1h_s[r*W1P + c0] = h;
    w1l_s[r*W1P + c0] = (_Float16)(x - (float)h);
  }

  // ---- folded housekeeping: zero F + cvt Wl/Wr + (blk 0) small zeros ----
  {
    f4 z4 = (f4){0.f,0.f,0.f,0.f};
    for (int i = blockIdx.x*FTH + t; i < SZ_F/4; i += FBLK*FTH)
      *(f4*)(F + (size_t)i*4) = z4;
    for (int i = blockIdx.x*FTH + t; i < 2*262144; i += FBLK*FTH){
      if (i < 262144) hbase[HOFF_WLH + i] = (_Float16)Wl[i];
      else            hbase[HOFF_WRH + (i-262144)] = (_Float16)Wr[i-262144];
    }
    if (blockIdx.x == 0)
      for (int i = t; i < SMALL_ZERO; i += FTH) ws[OFF_CNT + i] = 0.f;
  }

  // ---- phase 1: z=relu(X@W1^T+b1); LN; logit=zn.W2+b2 (identical math) ----
  h8 ah[4], al[4];
  #pragma unroll
  for (int c=0;c<4;++c){
    float xvv[8] = {xu[c].x,xu[c].y,xu[c].z,xu[c].w,xv[c].x,xv[c].y,xv[c].z,xv[c].w};
    #pragma unroll
    for (int j=0;j<8;++j){
      _Float16 hi = (_Float16)xvv[j];
      ah[c][j] = hi;
      al[c][j] = (_Float16)(xvv[j] - (float)hi);
    }
  }
  __syncthreads();   // W1 LDS ready

  f4 acc[8];
  #pragma unroll
  for (int nt=0;nt<8;++nt) acc[nt] = (f4){0.f,0.f,0.f,0.f};

  #pragma unroll
  for (int c=0;c<4;++c){
    #pragma unroll
    for (int nt=0;nt<8;++nt){
      int o = nt*16 + l15;
      h8 bh  = *(const h8*)(w1h_s + o*W1P + c*32 + quad*8);
      h8 bl_ = *(const h8*)(w1l_s + o*W1P + c*32 + quad*8);
      acc[nt] = __builtin_amdgcn_mfma_f32_16x16x32_f16(ah[c], bh,  acc[nt], 0,0,0);
      acc[nt] = __builtin_amdgcn_mfma_f32_16x16x32_f16(al[c], bh,  acc[nt], 0,0,0);
      acc[nt] = __builtin_amdgcn_mfma_f32_16x16x32_f16(ah[c], bl_, acc[nt], 0,0,0);
      acc[nt] = __builtin_amdgcn_mfma_f32_16x16x32_f16(al[c], bl_, acc[nt], 0,0,0);
    }
  }

  float bv[8], gv[8], lv[8], wv[8];
  #pragma unroll
  for (int nt=0;nt<8;++nt){
    int o = nt*16 + l15;
    bv[nt]=b1[o]; gv[nt]=ln_g[o]; lv[nt]=ln_b[o]; wv[nt]=W2[o];
  }
  float b2v = b2[0];
  #pragma unroll
  for (int r=0;r<4;++r){
    float z[8];
    float s1=0.f, s2=0.f;
    #pragma unroll
    for (int nt=0;nt<8;++nt){
      float zz = acc[nt][r] + bv[nt];
      zz = zz>0.f ? zz : 0.f;
      z[nt] = zz; s1 += zz; s2 += zz*zz;
    }
    #pragma unroll
    for (int m=1;m<16;m<<=1){ s1 += __shfl_xor(s1,m); s2 += __shfl_xor(s2,m); }
    float mu = s1/(float)HH;
    float var = s2/(float)HH - mu*mu;
    float rs = 1.0f/sqrtf(var+EPSF);
    float s3 = 0.f;
    #pragma unroll
    for (int nt=0;nt<8;++nt){
      float zn = (z[nt]-mu)*rs*gv[nt] + lv[nt];
      s3 += zn*wv[nt];
    }
    #pragma unroll
    for (int m=1;m<16;m<<=1) s3 += __shfl_xor(s3,m);
    if (l15 == 0) llog[16*w + quad*4 + r] = s3 + b2v;
  }
  __syncthreads();

  // ---- phase 2: topk/softmax per node (threads 0..11), plain stores only ----
  if (t < FMT/16){
    int n = blockIdx.x*(FMT/16) + t;
    float l[CCC];
    #pragma unroll
    for (int c=0;c<CCC;++c) l[c] = llog[t*16+c];
    unsigned mask = 0;
    #pragma unroll
    for (int k=0;k<KTOP;++k){
      float best = -3e38f; int bi = 0;
      #pragma unroll
      for (int c=0;c<CCC;++c){
        bool taken = (mask>>c)&1u;
        if (!taken && l[c] > best){ best = l[c]; bi = c; }
      }
      mask |= 1u<<bi;
    }
    float m = -3e38f;
    #pragma unroll
    for (int c=0;c<CCC;++c) m = l[c]>m ? l[c] : m;
    float s = 0.f;
    #pragma unroll
    for (int c=0;c<CCC;++c) s += expf(l[c]-m);
    float inv = 1.0f/s;
    unsigned m2 = mask;
    for (int j=0;j<KTOP;++j){
      int ci = __ffs(m2)-1; m2 &= m2-1u;
      unsigned rest = mask & ~(1u<<ci);
      int v[3]; unsigned r2 = rest;
      #pragma unroll
      for (int q=0;q<3;++q){ int col = __ffs(r2)-1; r2 &= r2-1u; v[q] = col - (col>ci ? 1:0); }
      int rank = C3i(v[2]) + C2i(v[1]) + v[0];
      int e4 = n*KTOP + j;
      cols[e4] = ci; ranks[e4] = rank; fiSel[e4] = expf(l[ci]-m)*inv;
    }
  }
}

// ===== stage C: class feature sums (high-TLP atomics, 6144 blocks) + nodeList
// ===== build in 12 extra blocks (merged k_nlist; R10-proven) =====
__global__ __launch_bounds__(256) void k_accF(const float* __restrict__ X,
    const int* __restrict__ cols, const int* __restrict__ ranks,
    const float* __restrict__ fiSel, float* __restrict__ F, float* __restrict__ cnt,
    int* __restrict__ nodeCnt, int* __restrict__ nodeList){
  __shared__ int lcnt[CCC];
  __shared__ int lbase[CCC];
  int t = threadIdx.x;
  if (blockIdx.x < NN*KTOP/2){
    int e = blockIdx.x*2 + (t>>7);
    int h = t & 127;
    int ci = cols[e], rank = ranks[e];
    float fi = fiSel[e];
    int n = e >> 2;
    float v = X[(n*CCC+ci)*HH + h] * fi;
    atomicAdd(&F[(ci*NCLS+rank)*HH + h], v);
    if (h==0) atomicAdd(&cnt[ci*NCLS+rank], 1.0f);
  } else {
    int nb = blockIdx.x - NN*KTOP/2;   // 0..11
    if (t < CCC) lcnt[t] = 0;
    __syncthreads();
    int n = nb*256 + t;
    int mycis[KTOP], mypos[KTOP];
    #pragma unroll
    for (int j=0;j<KTOP;++j){
      int ci = cols[n*KTOP+j];
      mycis[j] = ci;
      mypos[j] = atomicAdd(&lcnt[ci], 1);
    }
    __syncthreads();
    if (t < CCC) lbase[t] = atomicAdd(&nodeCnt[t*16], lcnt[t]);
    __syncthreads();
    #pragma unroll
    for (int j=0;j<KTOP;++j){
      int ci = mycis[j];
      nodeList[ci*NN + lbase[ci] + mypos[j]] = n*KTOP + j;
    }
  }
}

// ====== stage D: pairs + singles + degrees + inclusion-exclusion agg (R1-proven) ======
__global__ __launch_bounds__(256) void k_graph(const float* __restrict__ F,
    const float* __restrict__ cnt, float* __restrict__ agg){
  int cb = blockIdx.x, ci = blockIdx.y, t = threadIdx.x;
  __shared__ float cntl[NCLS];
  __shared__ float PcS[105], UcS[15];
  __shared__ int   abcs[NCLS];   // a | b<<5 | c<<10
  __shared__ int   prs[NCLS];    // pab | pac<<10 | pbc<<20
  __shared__ float Fl[NCLS*GCP];
  __shared__ float P[105*GCP];
  __shared__ float U[15*GCP];
  const float* Fc = F + (size_t)ci*NCLS*HH + cb*GCP;

  for (int i=t; i<NCLS*2; i+=256){
    int r = i>>1, hf = i&1;
    float4 v = *(const float4*)(Fc + (size_t)r*HH + hf*4);
    *(float4*)(&Fl[r*GCP + hf*4]) = v;
  }
  for (int r=t; r<NCLS; r+=256){
    cntl[r] = cnt[ci*NCLS+r];
    int c=2; while (c<14 && C3i(c+1)<=r) c++;
    int rem = r - C3i(c);
    int b=1; while (b<c-1 && C2i(b+1)<=rem) b++;
    int a = rem - C2i(b);
    abcs[r] = a | (b<<5) | (c<<10);
    prs[r] = (C2i(b)+a) | ((C2i(c)+a)<<10) | ((C2i(c)+b)<<20);
  }
  __syncthreads();
  if (t<105){
    int pb=1; while (pb<14 && C2i(pb+1)<=t) pb++;
    int pa = t - C2i(pb);
    float s=0.f;
    #pragma unroll
    for (int z=0;z<15;++z){
      if (z==pa||z==pb) continue;
      int lo,mid,hi;
      if (z<pa){lo=z;mid=pa;hi=pb;} else if (z<pb){lo=pa;mid=z;hi=pb;} else {lo=pa;mid=pb;hi=z;}
      s += cntl[C3i(hi)+C2i(mid)+lo];
    }
    PcS[t]=s;
  }
  __syncthreads();
  if (t<15){
    float s=0.f;
    #pragma unroll
    for (int y=0;y<15;++y){
      if (y==t) continue;
      int lo = t<y?t:y, hi = t<y?y:t;
      s += PcS[C2i(hi)+lo];
    }
    UcS[t]=0.5f*s;
  }
  __syncthreads();
  for (int idx=t; idx<105*GCP; idx+=256){
    int p = idx/GCP, col = idx&(GCP-1);
    int pb=1; while (pb<14 && C2i(pb+1)<=p) pb++;
    int pa = p - C2i(pb);
    float s=0.f;
    #pragma unroll
    for (int z=0;z<15;++z){
      if (z==pa||z==pb) continue;
      int lo,mid,hi;
      if (z<pa){lo=z;mid=pa;hi=pb;} else if (z<pb){lo=pa;mid=z;hi=pb;} else {lo=pa;mid=pb;hi=z;}
      s += Fl[(C3i(hi)+C2i(mid)+lo)*GCP + col];
    }
    P[idx]=s;
  }
  __syncthreads();
  for (int idx=t; idx<15*GCP; idx+=256){
    int x = idx/GCP, col = idx&(GCP-1);
    float s=0.f;
    #pragma unroll
    for (int y=0;y<15;++y){
      if (y==x) continue;
      int lo = x<y?x:y, hi = x<y?y:x;
      s += P[(C2i(hi)+lo)*GCP + col];
    }
    U[idx]=0.5f*s;
  }
  __syncthreads();
  for (int idx=t; idx<NCLS*GCP; idx+=256){
    int r = idx/GCP, col = idx&(GCP-1);
    int v1=abcs[r]; int a=v1&31,b=(v1>>5)&31,c=(v1>>10)&31;
    int v2=prs[r];  int pab=v2&1023,pac=(v2>>10)&1023,pbc=(v2>>20)&1023;
    float deg = UcS[a]+UcS[b]+UcS[c]-PcS[pab]-PcS[pac]-PcS[pbc]+cntl[r];
    float invd = 1.0f/fmaxf(deg,1.0f);
    float v = U[a*GCP+col]+U[b*GCP+col]+U[c*GCP+col]
            - P[pab*GCP+col]-P[pac*GCP+col]-P[pbc*GCP+col]
            + Fl[r*GCP+col];
    agg[(size_t)ci*NCLS*HH + (size_t)r*HH + cb*GCP + col] = v*invd;
  }
}

// ===== stage E (merged E1+E2): hc = relu(agg[rank]@Wl^T + bl + fi*X @ Wr^T) =====
__global__ __launch_bounds__(256) void k_hc2(const float* __restrict__ X,
    const float* __restrict__ agg,
    const _Float16* __restrict__ Wlh, const _Float16* __restrict__ Wrh,
    const float* __restrict__ bl,
    const int* __restrict__ ranks, const float* __restrict__ fiSel,
    const int* __restrict__ nodeCnt, const int* __restrict__ nodeList,
    float* __restrict__ hcBuf, float* __restrict__ sums){
  int ci = blockIdx.y;
  int cntc = nodeCnt[ci*16];
  int base = blockIdx.x * MT;
  if (base >= cntc) return;
  __shared__ float rb[8];
  int t = threadIdx.x;
  int w = t >> 6;
  int lane = t & 63;
  int l15 = lane & 15, quad = lane >> 4;

  int pA = base + 16*w + l15;
  float fi = 0.f; int nA = 0; int rkA = -1;
  if (pA < cntc){
    int e = nodeList[ci*NN + pA];
    fi = fiSel[e]; nA = e >> 2; rkA = ranks[e];
  }
  // A-operand 1: fi * X[nA, ci, :]
  const float* xrow = X + ((size_t)nA*CCC + ci)*HH;
  h8 af[4];
  #pragma unroll
  for (int c=0;c<4;++c){
    float4 u = *(const float4*)(xrow + c*32 + quad*8);
    float4 v = *(const float4*)(xrow + c*32 + quad*8 + 4);
    float xv[8] = {u.x,u.y,u.z,u.w,v.x,v.y,v.z,v.w};
    #pragma unroll
    for (int j=0;j<8;++j) af[c][j] = (_Float16)(xv[j]*fi);
  }
  // A-operand 2: agg[ci, rank(pA), :]  (zero for inactive rows)
  h8 ag[4];
  if (rkA >= 0){
    const float* arow = agg + ((size_t)ci*NCLS + rkA)*HH;
    #pragma unroll
    for (int c=0;c<4;++c){
      float4 u = *(const float4*)(arow + c*32 + quad*8);
      float4 v = *(const float4*)(arow + c*32 + quad*8 + 4);
      float xv[8] = {u.x,u.y,u.z,u.w,v.x,v.y,v.z,v.w};
      #pragma unroll
      for (int j=0;j<8;++j) ag[c][j] = (_Float16)xv[j];
    }
  } else {
    #pragma unroll
    for (int c=0;c<4;++c) ag[c] = (h8){0,0,0,0,0,0,0,0};
  }

  f4 acc[8];
  #pragma unroll
  for (int nt=0;nt<8;++nt) acc[nt] = (f4){0.f,0.f,0.f,0.f};

  const _Float16* WcR = Wrh + (size_t)ci*HH*HH;
  const _Float16* WcL = Wlh + (size_t)ci*HH*HH;
  #pragma unroll
  for (int c=0;c<4;++c){
    #pragma unroll
    for (int nt=0;nt<8;++nt){
      int o = nt*16 + l15;
      h8 br = *(const h8*)(WcR + (size_t)o*HH + c*32 + quad*8);
      h8 blf= *(const h8*)(WcL + (size_t)o*HH + c*32 + quad*8);
      acc[nt] = __builtin_amdgcn_mfma_f32_16x16x32_f16(af[c], br,  acc[nt], 0,0,0);
      acc[nt] = __builtin_amdgcn_mfma_f32_16x16x32_f16(ag[c], blf, acc[nt], 0,0,0);
    }
  }

  float s1 = 0.f, s2 = 0.f;
  #pragma unroll
  for (int r=0;r<4;++r){
    int pD = base + 16*w + quad*4 + r;
    int e2 = -1;
    if (pD < cntc) e2 = nodeList[ci*NN + pD];
    if (e2 >= 0){
      float* drow = hcBuf + (size_t)e2*HH;
      #pragma unroll
      for (int nt=0;nt<8;++nt){
        int o = nt*16 + l15;
        float vv = acc[nt][r] + bl[ci*HH + o];
        vv = vv>0.f ? vv : 0.f;
        drow[o] = vv;
        s1 += vv; s2 += vv*vv;
      }
    }
  }
  #pragma unroll
  for (int m=1;m<64;m<<=1){ s1 += __shfl_xor(s1,m); s2 += __shfl_xor(s2,m); }
  if (lane == 0){ rb[w] = s1; rb[4+w] = s2; }
  __syncthreads();
  if (t==0){
    atomicAdd(&sums[ci],    rb[0]+rb[1]+rb[2]+rb[3]);
    atomicAdd(&sums[16+ci], rb[4]+rb[5]+rb[6]+rb[7]);
  }
}

// ========== stage F: masked mean/var normalize, write output ==========
__global__ __launch_bounds__(256) void k_out(const float* __restrict__ hcBuf,
    const int* __restrict__ cols, const int* __restrict__ nodeCnt,
    const float* __restrict__ sums, float* __restrict__ out){
  int idx = blockIdx.x*256 + threadIdx.x;
  int e = idx >> 7;
  int ci = cols[e];
  float cntf = (float)nodeCnt[ci*16];
  float nel = fmaxf(cntf * (float)HH, 1.0f);
  float mu = sums[ci]/nel;
  float var = sums[16+ci]/nel - mu*mu;
  out[idx] = (hcBuf[idx]-mu)/sqrtf(var+EPSF);
}

extern "C" void kernel_launch(void* const* d_in, const int* in_sizes, int n_in,
                              void* d_out, int out_size, void* d_ws, size_t ws_size,
                              hipStream_t stream){
  const float* X    = (const float*)d_in[0];
  const float* W1   = (const float*)d_in[1];
  const float* b1   = (const float*)d_in[2];
  const float* ln_g = (const float*)d_in[3];
  const float* ln_b = (const float*)d_in[4];
  const float* W2   = (const float*)d_in[5];
  const float* b2   = (const float*)d_in[6];
  const float* Wl   = (const float*)d_in[7];
  const float* bl   = (const float*)d_in[8];
  const float* Wr   = (const float*)d_in[9];
  float* ws = (float*)d_ws;
  float* F      = ws + OFF_F;
  float* cnt    = ws + OFF_CNT;
  float* sums   = ws + OFF_SUMS;
  int*   nodeCnt= (int*)(ws + OFF_NCNT);
  int*   cols   = (int*)(ws + OFF_COLS);
  int*   ranks  = (int*)(ws + OFF_RANKS);
  float* fiSel  = ws + OFF_FISEL;
  int*   nodeList=(int*)(ws + OFF_NLIST);
  float* agg    = ws + OFF_AGG;
  float* hcBuf  = ws + OFF_HC;
  _Float16* hbase = (_Float16*)(ws + OFF_HALF);
  float* out    = (float*)d_out;

  k_fused  <<<dim3(FBLK), dim3(FTH), 0, stream>>>(X, W1, b1, ln_g, ln_b, W2, b2,
                                                  Wl, Wr, hbase, F, ws,
                                                  cols, ranks, fiSel);
  k_accF   <<<dim3(NN*KTOP/2 + 12), dim3(256), 0, stream>>>(X, cols, ranks, fiSel, F, cnt,
                                                            nodeCnt, nodeList);
  k_graph  <<<dim3(GCB,16), dim3(256), 0, stream>>>(F, cnt, agg);
  k_hc2    <<<dim3((NN/MT),16), dim3(256), 0, stream>>>(X, agg, hbase+HOFF_WLH,
                                                        hbase+HOFF_WRH, bl, ranks, fiSel,
                                                        nodeCnt, nodeList, hcBuf, sums);
  k_out    <<<dim3(NN*KTOP*HH/256), dim3(256), 0, stream>>>(hcBuf, cols, nodeCnt, sums, out);
}